// Round 1
// baseline (8090.795 us; speedup 1.0000x reference)
//
#include <hip/hip_runtime.h>
#include <math.h>

// ---------------- constants ----------------
#define NB 32     // batch
#define NT 20     // time steps
#define NV 30     // gathered vertices (VORDER length)
#define C0 64     // per-vertex channels (JLD)
#define DM 1280   // D_MAMB = 20*64
#define DTR_ 1920 // D_TRANS = 30*64
#define DI 2560   // D_INNER
#define DSTATE 16
#define DTRANK 80
#define TEMPD 512
#define NHEAD_ 8
#define DH 240

__constant__ int d_VORDER[30] = {9,8,7,10,11,12,11,10,7,13,14,15,14,13,7,6,0,1,2,1,0,6,3,4,5,4,3,6,7,8};
__constant__ int d_REV[16]    = {20,19,18,26,25,24,27,28,29,0,7,6,5,13,12,11};

__device__ __forceinline__ float siluf(float x){ return x / (1.f + expf(-x)); }
__device__ __forceinline__ float geluf(float x){
    // jax.nn.gelu default (approximate=True, tanh form)
    float x3 = x*x*x;
    return 0.5f*x*(1.f + tanhf(0.7978845608028654f*(x + 0.044715f*x3)));
}
__device__ __forceinline__ float softplusf(float x){
    return fmaxf(x, 0.f) + log1pf(expf(-fabsf(x)));
}

// block-wide sum, blockDim.x == 256 (4 waves)
__device__ __forceinline__ float blockReduceSum(float v){
    #pragma unroll
    for (int off = 32; off > 0; off >>= 1) v += __shfl_down(v, off, 64);
    __shared__ float sred[4];
    __shared__ float stot;
    int w = threadIdx.x >> 6;
    if ((threadIdx.x & 63) == 0) sred[w] = v;
    __syncthreads();
    if (threadIdx.x == 0) stot = sred[0] + sred[1] + sred[2] + sred[3];
    __syncthreads();
    return stot;
}

// ---------------- generic tiled fp32 GEMM ----------------
// C[M,N] (ldc) = act(A[M,K](lda) @ B[K,N](ldb) + bias) [+= if ADD]
// requires K % 16 == 0, N % 4 == 0, lda/ldb % 4 == 0
enum { ACT_NONE=0, ACT_SILU=1, ACT_GELU=2, ACT_SOFTPLUS=3 };

template<int ACT, bool ADD>
__global__ __launch_bounds__(256) void gemm_k(
    const float* __restrict__ A, int lda,
    const float* __restrict__ B, int ldb,
    const float* __restrict__ bias,
    float* __restrict__ C, int ldc,
    int M, int N, int K)
{
    __shared__ float As[16][68];   // [k][m], row stride 68 floats (16B aligned rows)
    __shared__ float Bs[16][68];   // [k][n]
    const int bm = blockIdx.y * 64;
    const int bn = blockIdx.x * 64;
    const int tid = threadIdx.x;
    const int tm = (tid >> 4) << 2;       // 0..60
    const int tn = (tid & 15) << 2;       // 0..60
    const int arow = tid >> 2;            // 0..63
    const int acol = (tid & 3) << 2;      // 0,4,8,12
    const int brow = tid >> 4;            // 0..15
    const int bcol = (tid & 15) << 2;     // 0..60

    float acc[4][4] = {};

    for (int k0 = 0; k0 < K; k0 += 16) {
        float4 av = make_float4(0.f,0.f,0.f,0.f);
        if (bm + arow < M)
            av = *(const float4*)(A + (size_t)(bm + arow)*lda + k0 + acol);
        As[acol+0][arow] = av.x;
        As[acol+1][arow] = av.y;
        As[acol+2][arow] = av.z;
        As[acol+3][arow] = av.w;
        float4 bv = make_float4(0.f,0.f,0.f,0.f);
        if (bn + bcol < N)
            bv = *(const float4*)(B + (size_t)(k0 + brow)*ldb + bn + bcol);
        *(float4*)&Bs[brow][bcol] = bv;
        __syncthreads();
        #pragma unroll
        for (int kk = 0; kk < 16; ++kk) {
            float4 a4 = *(const float4*)&As[kk][tm];
            float4 b4 = *(const float4*)&Bs[kk][tn];
            float ar[4] = {a4.x, a4.y, a4.z, a4.w};
            float br[4] = {b4.x, b4.y, b4.z, b4.w};
            #pragma unroll
            for (int i = 0; i < 4; ++i)
                #pragma unroll
                for (int j = 0; j < 4; ++j)
                    acc[i][j] = fmaf(ar[i], br[j], acc[i][j]);
        }
        __syncthreads();
    }

    #pragma unroll
    for (int i = 0; i < 4; ++i) {
        int m = bm + tm + i;
        if (m >= M) continue;
        #pragma unroll
        for (int j = 0; j < 4; ++j) {
            int n = bn + tn + j;
            if (n >= N) continue;
            float v = acc[i][j];
            if (bias) v += bias[n];
            if (ACT == ACT_SILU)     v = siluf(v);
            if (ACT == ACT_GELU)     v = geluf(v);
            if (ACT == ACT_SOFTPLUS) v = softplusf(v);
            if (ADD) C[(size_t)m*ldc + n] += v;
            else     C[(size_t)m*ldc + n]  = v;
        }
    }
}

static void gemm(hipStream_t st, const float* A, int lda, const float* B, int ldb,
                 const float* bias, float* C, int ldc, int M, int N, int K,
                 int act, bool add)
{
    dim3 g((N + 63)/64, (M + 63)/64), b(256);
    if (add) { gemm_k<ACT_NONE,true><<<g,b,0,st>>>(A,lda,B,ldb,bias,C,ldc,M,N,K); return; }
    switch (act) {
      case ACT_SILU:     gemm_k<ACT_SILU,false><<<g,b,0,st>>>(A,lda,B,ldb,bias,C,ldc,M,N,K); break;
      case ACT_GELU:     gemm_k<ACT_GELU,false><<<g,b,0,st>>>(A,lda,B,ldb,bias,C,ldc,M,N,K); break;
      case ACT_SOFTPLUS: gemm_k<ACT_SOFTPLUS,false><<<g,b,0,st>>>(A,lda,B,ldb,bias,C,ldc,M,N,K); break;
      default:           gemm_k<ACT_NONE,false><<<g,b,0,st>>>(A,lda,B,ldb,bias,C,ldc,M,N,K); break;
    }
}

// ---------------- small kernels ----------------

// timestep embedding: out[b, j]=cos(t*f_j), out[b,640+j]=sin(t*f_j); f_j = exp(-ln(1e4)*j/640)
__global__ void tsemb_k(const int* __restrict__ t, float* __restrict__ o){
    int b = blockIdx.x, j = threadIdx.x;           // block 640
    float f = expf(-9.210340371976184f * (float)j / 640.f);
    float a = (float)t[b] * f;
    o[b*DM + j]       = cosf(a);
    o[b*DM + 640 + j] = sinf(a);
}

__global__ void silu_v(const float* __restrict__ a, float* __restrict__ o, int n){
    int i = blockIdx.x*256 + threadIdx.x; if (i < n) o[i] = siluf(a[i]);
}
__global__ void copy_v(const float* __restrict__ a, float* __restrict__ o, int n){
    int i = blockIdx.x*256 + threadIdx.x; if (i < n) o[i] = a[i];
}
__global__ void add_v(const float* __restrict__ a, float* __restrict__ o, int n){
    int i = blockIdx.x*256 + threadIdx.x; if (i < n) o[i] += a[i];
}

// h[b,t,vo,c] = x[b,t,VORDER[vo]*3 + :3] @ emb_W + emb_b + seq_emb[t,VORDER[vo],c]
__global__ void embed_k(const float* __restrict__ x, const float* __restrict__ seq_emb,
                        const float* __restrict__ eW, const float* __restrict__ eb,
                        float* __restrict__ h){
    int i = blockIdx.x;            // b*600 + t*30 + vo
    int c = threadIdx.x;           // 64
    int vo = i % 30; int bt = i / 30; int t = bt % 20; int b = bt / 20;
    int v = d_VORDER[vo];
    const float* xp = x + (size_t)(b*20 + t)*48 + v*3;
    float val = eb[c] + seq_emb[(size_t)(t*16 + v)*64 + c]
              + xp[0]*eW[c] + xp[1]*eW[64 + c] + xp[2]*eW[128 + c];
    h[(size_t)i*64 + c] = val;
}

// hm[(b*30+v)*1280 + t*64+c] = h[((b*20+t)*30+v)*64 + c]
__global__ void h2hm_k(const float* __restrict__ h, float* __restrict__ hm){
    int row = blockIdx.x;          // b*30+v
    int b = row / 30, v = row % 30;
    for (int idx = threadIdx.x; idx < DM; idx += 256) {
        int t = idx >> 6, c = idx & 63;
        hm[(size_t)row*DM + idx] = h[((size_t)(b*20 + t)*30 + v)*64 + c];
    }
}
// ht[(b*20+t)*1920 + v*64+c] = hm[(b*30+v)*1280 + t*64+c]
__global__ void hm2ht_k(const float* __restrict__ hm, float* __restrict__ ht){
    int row = blockIdx.x;          // b*20+t
    int b = row / 20, t = row % 20;
    for (int idx = threadIdx.x; idx < DTR_; idx += 256) {
        int v = idx >> 6, c = idx & 63;
        ht[(size_t)row*DTR_ + idx] = hm[((size_t)(b*30 + v))*DM + t*64 + c];
    }
}

// rmsnorm row of D, out = x*rsqrt(mean(x^2)+1e-5)*w (+ addv[row/addDiv] if addv)
__global__ void rms_k(const float* __restrict__ x, const float* __restrict__ w,
                      const float* __restrict__ addv, int addDiv,
                      float* __restrict__ o, int D){
    int row = blockIdx.x;
    const float* xr = x + (size_t)row*D;
    float ss = 0.f;
    for (int i = threadIdx.x; i < D; i += 256){ float v = xr[i]; ss += v*v; }
    ss = blockReduceSum(ss);
    float rs = rsqrtf(ss/(float)D + 1e-5f);
    const float* ap = addv ? addv + (size_t)(row/addDiv)*D : nullptr;
    for (int i = threadIdx.x; i < D; i += 256){
        float v = xr[i]*rs*w[i];
        if (ap) v += ap[i];
        o[(size_t)row*D + i] = v;
    }
}

// layernorm row of D
__global__ void ln_k(const float* __restrict__ x, const float* __restrict__ w,
                     const float* __restrict__ b, float* __restrict__ o, int D){
    int row = blockIdx.x;
    const float* xr = x + (size_t)row*D;
    float s1 = 0.f, s2 = 0.f;
    for (int i = threadIdx.x; i < D; i += 256){ float v = xr[i]; s1 += v; s2 += v*v; }
    s1 = blockReduceSum(s1);
    s2 = blockReduceSum(s2);
    float m = s1/(float)D, var = s2/(float)D - m*m, rs = rsqrtf(var + 1e-5f);
    for (int i = threadIdx.x; i < D; i += 256)
        o[(size_t)row*D + i] = (xr[i] - m)*rs*w[i] + b[i];
}

// causal depthwise conv (K=4) + silu; xm = xz[..., :2560]
__global__ void convsilu_k(const float* __restrict__ xz, const float* __restrict__ cw,
                           const float* __restrict__ cb, float* __restrict__ xc){
    int idx = blockIdx.x*256 + threadIdx.x;
    if (idx >= NB*NV*DI) return;
    int d = idx % DI; int bl = idx / DI; int l = bl % NV; int b = bl / NV;
    float acc = cb[d];
    #pragma unroll
    for (int k = 0; k < 4; ++k) {
        int ls = l - 3 + k;
        if (ls >= 0) acc += xz[((size_t)(b*NV + ls))*(2*DI) + d] * cw[d*4 + k];
    }
    xc[idx] = siluf(acc);
}

// selective scan; one thread per (b,d); y2 = (scan_y + xc*D)*silu(res)
__global__ __launch_bounds__(256) void scan_k(
    const float* __restrict__ delta, const float* __restrict__ dbc,
    const float* __restrict__ xc, const float* __restrict__ xz,
    const float* __restrict__ A_log, const float* __restrict__ Dp,
    float* __restrict__ y2)
{
    __shared__ float sBC[30][32];  // [l][0:16 Bm | 16:32 Cm]
    int b = blockIdx.x / 10;
    int dblk = blockIdx.x % 10;
    int tid = threadIdx.x;
    for (int i = tid; i < 30*32; i += 256) {
        int l = i >> 5, j = i & 31;
        sBC[l][j] = dbc[((size_t)(b*NV + l))*112 + 80 + j];
    }
    __syncthreads();
    int d = dblk*256 + tid;
    float aA[16], s[16];
    #pragma unroll
    for (int n = 0; n < 16; ++n){ aA[n] = -expf(A_log[(size_t)d*16 + n]); s[n] = 0.f; }
    float dpv = Dp[d];
    for (int l = 0; l < NV; ++l) {
        size_t base = (size_t)(b*NV + l);
        float dv   = delta[base*DI + d];
        float xcv  = xc[base*DI + d];
        float resv = xz[base*(2*DI) + DI + d];
        float y = 0.f;
        #pragma unroll
        for (int n = 0; n < 16; ++n) {
            float dA = expf(dv*aA[n]);
            s[n] = dA*s[n] + dv*sBC[l][n]*xcv;
            y = fmaf(s[n], sBC[l][16 + n], y);
        }
        y2[base*DI + d] = (y + xcv*dpv) * siluf(resv);
    }
}

// attention: one 64-lane block per (b,t,h); S = 20, dh = 240
__global__ __launch_bounds__(64) void attn_k(const float* __restrict__ q,
                                             const float* __restrict__ k,
                                             const float* __restrict__ v,
                                             float* __restrict__ o){
    int idx = blockIdx.x;          // b*160 + t*8 + h
    int h = idx % 8; int bt = idx / 8; int t = bt % 20; int b = bt / 20;
    int lane = threadIdx.x;
    const float* qp = q + ((size_t)(b*20 + t))*DTR_ + h*DH;
    float qr[4];
    #pragma unroll
    for (int i = 0; i < 4; ++i){ int j = lane + i*64; qr[i] = (j < DH) ? qp[j] : 0.f; }
    __shared__ float sc[20];
    const float scale = 0.06454972243679028f;  // 1/sqrt(240)
    for (int s2 = 0; s2 < 20; ++s2) {
        const float* kp = k + ((size_t)(b*20 + s2))*DTR_ + h*DH;
        float p = 0.f;
        #pragma unroll
        for (int i = 0; i < 4; ++i){ int j = lane + i*64; if (j < DH) p = fmaf(qr[i], kp[j], p); }
        #pragma unroll
        for (int off = 32; off > 0; off >>= 1) p += __shfl_down(p, off, 64);
        if (lane == 0) sc[s2] = p*scale;
    }
    __syncthreads();
    float m = -1e30f;
    #pragma unroll
    for (int s2 = 0; s2 < 20; ++s2) m = fmaxf(m, sc[s2]);
    float ps[20]; float sum = 0.f;
    #pragma unroll
    for (int s2 = 0; s2 < 20; ++s2){ ps[s2] = expf(sc[s2] - m); sum += ps[s2]; }
    float inv = 1.f/sum;
    float acc[4] = {0.f,0.f,0.f,0.f};
    for (int s2 = 0; s2 < 20; ++s2) {
        const float* vp = v + ((size_t)(b*20 + s2))*DTR_ + h*DH;
        float w2 = ps[s2]*inv;
        #pragma unroll
        for (int i = 0; i < 4; ++i){ int j = lane + i*64; if (j < DH) acc[i] = fmaf(w2, vp[j], acc[i]); }
    }
    float* op = o + ((size_t)(b*20 + t))*DTR_ + h*DH;
    #pragma unroll
    for (int i = 0; i < 4; ++i){ int j = lane + i*64; if (j < DH) op[j] = acc[i]; }
}

// stylize pre-GEMM: o = silu( layernorm(x,lw,lb)*(1+scale_b) + shift_b ), row=(b,t), D=1920
__global__ void sty_ln_k(const float* __restrict__ x, const float* __restrict__ lw,
                         const float* __restrict__ lb, const float* __restrict__ ss,
                         float* __restrict__ o){
    int row = blockIdx.x;          // b*20+t
    int b = row / 20;
    const float* xr = x + (size_t)row*DTR_;
    float s1 = 0.f, s2 = 0.f;
    for (int i = threadIdx.x; i < DTR_; i += 256){ float v = xr[i]; s1 += v; s2 += v*v; }
    s1 = blockReduceSum(s1);
    s2 = blockReduceSum(s2);
    float m = s1/(float)DTR_, var = s2/(float)DTR_ - m*m, rs = rsqrtf(var + 1e-5f);
    const float* sb = ss + (size_t)b*(2*DTR_);
    for (int i = threadIdx.x; i < DTR_; i += 256) {
        float v = (xr[i] - m)*rs*lw[i] + lb[i];
        v = v*(1.f + sb[i]) + sb[DTR_ + i];
        o[(size_t)row*DTR_ + i] = siluf(v);
    }
}

// out[b,t,v*3+j] = sum_c fr[b,t,REV[v]*64+c] * W[c,j] + bias[j]
__global__ void head_k(const float* __restrict__ fr, const float* __restrict__ W,
                       const float* __restrict__ bias, float* __restrict__ out){
    int row = blockIdx.x;          // b*20+t
    int tid = threadIdx.x;         // 48
    int v = tid/3, j = tid%3;
    const float* g = fr + (size_t)row*DTR_ + d_REV[v]*64;
    float acc = bias[j];
    #pragma unroll
    for (int c = 0; c < 64; ++c) acc = fmaf(g[c], W[c*3 + j], acc);
    out[(size_t)row*48 + tid] = acc;
}

// ---------------- orchestration ----------------
extern "C" void kernel_launch(void* const* d_in, const int* in_sizes, int n_in,
                              void* d_out, int out_size, void* d_ws, size_t ws_size,
                              hipStream_t stream)
{
    const float* x        = (const float*)d_in[0];
    const int*   tst      = (const int*)  d_in[1];
    const float* seq_emb  = (const float*)d_in[2];
    const float* emb_W    = (const float*)d_in[3];
    const float* emb_b    = (const float*)d_in[4];
    const float* time_W1  = (const float*)d_in[5];
    const float* time_b1  = (const float*)d_in[6];
    const float* time_W2  = (const float*)d_in[7];
    const float* time_b2  = (const float*)d_in[8];
    const float* m_norm_w = (const float*)d_in[9];
    const float* m_emb_W  = (const float*)d_in[10];
    const float* m_emb_b  = (const float*)d_in[11];
    const float* m_in_W   = (const float*)d_in[12];
    const float* m_conv_w = (const float*)d_in[13];
    const float* m_conv_b = (const float*)d_in[14];
    const float* m_xproj_W= (const float*)d_in[15];
    const float* m_dt_W   = (const float*)d_in[16];
    const float* m_dt_b   = (const float*)d_in[17];
    const float* m_A_log  = (const float*)d_in[18];
    const float* m_D      = (const float*)d_in[19];
    const float* m_out_W  = (const float*)d_in[20];
    const float* t_ln1_w  = (const float*)d_in[21];
    const float* t_ln1_b  = (const float*)d_in[22];
    const float* t_Wq     = (const float*)d_in[23];
    const float* t_bq     = (const float*)d_in[24];
    const float* t_Wk     = (const float*)d_in[25];
    const float* t_bk     = (const float*)d_in[26];
    const float* t_Wv     = (const float*)d_in[27];
    const float* t_bv     = (const float*)d_in[28];
    const float* t_s1_eW  = (const float*)d_in[29];
    const float* t_s1_eb  = (const float*)d_in[30];
    const float* t_s1_lw  = (const float*)d_in[31];
    const float* t_s1_lb  = (const float*)d_in[32];
    const float* t_s1_oW  = (const float*)d_in[33];
    const float* t_s1_ob  = (const float*)d_in[34];
    const float* t_ln2_w  = (const float*)d_in[35];
    const float* t_ln2_b  = (const float*)d_in[36];
    const float* t_fW1    = (const float*)d_in[37];
    const float* t_fb1    = (const float*)d_in[38];
    const float* t_fW2    = (const float*)d_in[39];
    const float* t_fb2    = (const float*)d_in[40];
    const float* t_s2_eW  = (const float*)d_in[41];
    const float* t_s2_eb  = (const float*)d_in[42];
    const float* t_s2_lw  = (const float*)d_in[43];
    const float* t_s2_lb  = (const float*)d_in[44];
    const float* t_s2_oW  = (const float*)d_in[45];
    const float* t_s2_ob  = (const float*)d_in[46];
    const float* normf_w  = (const float*)d_in[47];
    const float* head_W   = (const float*)d_in[48];
    const float* head_b   = (const float*)d_in[49];

    float* ws = (float*)d_ws;
    size_t off = 0;
    auto alloc = [&](size_t n){ float* p = ws + off; off += n; return p; };

    const size_t HSZ = (size_t)NB*NT*NV*C0;   // 1,228,800
    float* embt = alloc((size_t)NB*DM);       // 32x1280
    float* emb1 = alloc((size_t)NB*TEMPD);    // 32x512
    float* emb  = alloc((size_t)NB*TEMPD);
    float* semb = alloc((size_t)NB*TEMPD);
    float* h    = alloc(HSZ);                 // (b,t,v,c) == ht flat layout
    float* pre0 = alloc(HSZ);
    float* pre1 = alloc(HSZ);
    float* hm   = alloc(HSZ);                 // (b,v,t*64+c)
    float* hn   = alloc(HSZ);
    float* memb = alloc((size_t)NB*DM);
    float* xz   = alloc((size_t)NB*NV*2*DI);  // 4,915,200
    float* xcb  = alloc((size_t)NB*NV*DI);    // 2,457,600
    float* dbc  = alloc((size_t)NB*NV*112);
    float* delta= alloc((size_t)NB*NV*DI);
    float* y2   = alloc((size_t)NB*NV*DI);
    float* xn   = alloc(HSZ);
    float* qb   = alloc(HSZ);
    float* kb   = alloc(HSZ);
    float* vb   = alloc(HSZ);
    float* aty  = alloc(HSZ);
    float* sty  = alloc(HSZ);
    float* ssb  = alloc((size_t)NB*2*DTR_);
    float* mid  = alloc((size_t)NB*NT*2560); // FFN hidden
    (void)ws_size; (void)in_sizes; (void)n_in; (void)out_size;

    // ---- time embedding + MLP ----
    tsemb_k<<<NB, 640, 0, stream>>>(tst, embt);
    gemm(stream, embt, DM, time_W1, TEMPD, time_b1, emb1, TEMPD, NB, TEMPD, DM, ACT_SILU, false);
    gemm(stream, emb1, TEMPD, time_W2, TEMPD, time_b2, emb, TEMPD, NB, TEMPD, TEMPD, ACT_NONE, false);
    silu_v<<<(NB*TEMPD + 255)/256, 256, 0, stream>>>(emb, semb, NB*TEMPD);

    // ---- vertex embedding + VORDER gather ----
    embed_k<<<NB*NT*NV, 64, 0, stream>>>(x, seq_emb, emb_W, emb_b, h);

    for (int i = 0; i < 4; ++i) {
        if (i == 0) copy_v<<<(int)((HSZ + 255)/256), 256, 0, stream>>>(h, pre0, (int)HSZ);
        if (i == 1) copy_v<<<(int)((HSZ + 255)/256), 256, 0, stream>>>(h, pre1, (int)HSZ);

        // ---- mamba half ----
        gemm(stream, emb, TEMPD, m_emb_W + (size_t)i*TEMPD*DM, DM, m_emb_b + (size_t)i*DM,
             memb, DM, NB, DM, TEMPD, ACT_NONE, false);
        h2hm_k<<<NB*NV, 256, 0, stream>>>(h, hm);
        rms_k<<<NB*NV, 256, 0, stream>>>(hm, m_norm_w + (size_t)i*DM, memb, NV, hn, DM);
        gemm(stream, hn, DM, m_in_W + (size_t)i*DM*2*DI, 2*DI, nullptr,
             xz, 2*DI, NB*NV, 2*DI, DM, ACT_NONE, false);
        convsilu_k<<<(NB*NV*DI + 255)/256, 256, 0, stream>>>(
            xz, m_conv_w + (size_t)i*DI*4, m_conv_b + (size_t)i*DI, xcb);
        gemm(stream, xcb, DI, m_xproj_W + (size_t)i*DI*112, 112, nullptr,
             dbc, 112, NB*NV, 112, DI, ACT_NONE, false);
        gemm(stream, dbc, 112, m_dt_W + (size_t)i*DTRANK*DI, DI, m_dt_b + (size_t)i*DI,
             delta, DI, NB*NV, DI, DTRANK, ACT_SOFTPLUS, false);
        scan_k<<<NB*10, 256, 0, stream>>>(delta, dbc, xcb, xz,
             m_A_log + (size_t)i*DI*DSTATE, m_D + (size_t)i*DI, y2);
        gemm(stream, y2, DI, m_out_W + (size_t)i*DI*DM, DM, nullptr,
             hm, DM, NB*NV, DM, DI, ACT_NONE, true /*hm += mamba_out*/);
        hm2ht_k<<<NB*NT, 256, 0, stream>>>(hm, h);   // h now holds ht (b,t,1920)

        // ---- transformer half ----
        ln_k<<<NB*NT, 256, 0, stream>>>(h, t_ln1_w + (size_t)i*DTR_, t_ln1_b + (size_t)i*DTR_, xn, DTR_);
        gemm(stream, xn, DTR_, t_Wq + (size_t)i*DTR_*DTR_, DTR_, t_bq + (size_t)i*DTR_,
             qb, DTR_, NB*NT, DTR_, DTR_, ACT_NONE, false);
        gemm(stream, xn, DTR_, t_Wk + (size_t)i*DTR_*DTR_, DTR_, t_bk + (size_t)i*DTR_,
             kb, DTR_, NB*NT, DTR_, DTR_, ACT_NONE, false);
        gemm(stream, xn, DTR_, t_Wv + (size_t)i*DTR_*DTR_, DTR_, t_bv + (size_t)i*DTR_,
             vb, DTR_, NB*NT, DTR_, DTR_, ACT_NONE, false);
        attn_k<<<NB*NT*NHEAD_, 64, 0, stream>>>(qb, kb, vb, aty);

        // stylize 1: ht += silu(ln(aty)*(1+scale)+shift) @ oW + ob
        gemm(stream, semb, TEMPD, t_s1_eW + (size_t)i*TEMPD*2*DTR_, 2*DTR_, t_s1_eb + (size_t)i*2*DTR_,
             ssb, 2*DTR_, NB, 2*DTR_, TEMPD, ACT_NONE, false);
        sty_ln_k<<<NB*NT, 256, 0, stream>>>(aty, t_s1_lw + (size_t)i*DTR_, t_s1_lb + (size_t)i*DTR_, ssb, sty);
        gemm(stream, sty, DTR_, t_s1_oW + (size_t)i*DTR_*DTR_, DTR_, t_s1_ob + (size_t)i*DTR_,
             h, DTR_, NB*NT, DTR_, DTR_, ACT_NONE, true);

        // FFN: aty = gelu(ln2(h)@fW1+fb1)@fW2+fb2
        ln_k<<<NB*NT, 256, 0, stream>>>(h, t_ln2_w + (size_t)i*DTR_, t_ln2_b + (size_t)i*DTR_, xn, DTR_);
        gemm(stream, xn, DTR_, t_fW1 + (size_t)i*DTR_*2560, 2560, t_fb1 + (size_t)i*2560,
             mid, 2560, NB*NT, 2560, DTR_, ACT_GELU, false);
        gemm(stream, mid, 2560, t_fW2 + (size_t)i*2560*DTR_, DTR_, t_fb2 + (size_t)i*DTR_,
             aty, DTR_, NB*NT, DTR_, 2560, ACT_NONE, false);

        // stylize 2
        gemm(stream, semb, TEMPD, t_s2_eW + (size_t)i*TEMPD*2*DTR_, 2*DTR_, t_s2_eb + (size_t)i*2*DTR_,
             ssb, 2*DTR_, NB, 2*DTR_, TEMPD, ACT_NONE, false);
        sty_ln_k<<<NB*NT, 256, 0, stream>>>(aty, t_s2_lw + (size_t)i*DTR_, t_s2_lb + (size_t)i*DTR_, ssb, sty);
        gemm(stream, sty, DTR_, t_s2_oW + (size_t)i*DTR_*DTR_, DTR_, t_s2_ob + (size_t)i*DTR_,
             h, DTR_, NB*NT, DTR_, DTR_, ACT_NONE, true);

        // skip connections
        if (i == 2) add_v<<<(int)((HSZ + 255)/256), 256, 0, stream>>>(pre1, h, (int)HSZ);
        if (i == 3) add_v<<<(int)((HSZ + 255)/256), 256, 0, stream>>>(pre0, h, (int)HSZ);
    }

    // final rmsnorm + REV gather + head
    rms_k<<<NB*NT, 256, 0, stream>>>(h, normf_w, nullptr, 1, xn, DTR_);
    head_k<<<NB*NT, 48, 0, stream>>>(xn, head_W, head_b, (float*)d_out);
}

// Round 3
// 7427.027 us; speedup vs baseline: 1.0894x; 1.0894x over previous
//
#include <hip/hip_runtime.h>
#include <hip/hip_bf16.h>
#include <math.h>

// ---------------- constants ----------------
#define NB 32     // batch
#define NT 20     // time steps
#define NV 30     // gathered vertices (VORDER length)
#define C0 64     // per-vertex channels (JLD)
#define DM 1280   // D_MAMB = 20*64
#define DTR_ 1920 // D_TRANS = 30*64
#define DI 2560   // D_INNER
#define DSTATE 16
#define DTRANK 80
#define TEMPD 512
#define NHEAD_ 8
#define DH 240

__constant__ int d_VORDER[30] = {9,8,7,10,11,12,11,10,7,13,14,15,14,13,7,6,0,1,2,1,0,6,3,4,5,4,3,6,7,8};
__constant__ int d_REV[16]    = {20,19,18,26,25,24,27,28,29,0,7,6,5,13,12,11};

typedef __bf16 bf16x8 __attribute__((ext_vector_type(8)));
typedef float f32x4  __attribute__((ext_vector_type(4)));

__device__ __forceinline__ float siluf(float x){ return x / (1.f + expf(-x)); }
__device__ __forceinline__ float geluf(float x){
    float x3 = x*x*x;
    return 0.5f*x*(1.f + tanhf(0.7978845608028654f*(x + 0.044715f*x3)));
}
__device__ __forceinline__ float softplusf(float x){
    return fmaxf(x, 0.f) + log1pf(expf(-fabsf(x)));
}

__device__ __forceinline__ unsigned int pack2bf(float x, float y){
    __bf16 a = (__bf16)x, b = (__bf16)y;
    unsigned short ua = __builtin_bit_cast(unsigned short, a);
    unsigned short ub = __builtin_bit_cast(unsigned short, b);
    return (unsigned int)ua | ((unsigned int)ub << 16);
}

// block-wide sum, blockDim.x == 256 (4 waves)
__device__ __forceinline__ float blockReduceSum(float v){
    #pragma unroll
    for (int off = 32; off > 0; off >>= 1) v += __shfl_down(v, off, 64);
    __shared__ float sred[4];
    __shared__ float stot;
    int w = threadIdx.x >> 6;
    if ((threadIdx.x & 63) == 0) sred[w] = v;
    __syncthreads();
    if (threadIdx.x == 0) stot = sred[0] + sred[1] + sred[2] + sred[3];
    __syncthreads();
    return stot;
}

enum { ACT_NONE=0, ACT_SILU=1, ACT_GELU=2, ACT_SOFTPLUS=3 };

// ---------------- MFMA bf16 GEMM core ----------------
// C[M,N](ldc) = act(A[M,K](lda) @ B[K,N](ldb) + bias) [+= if ADD]
// A,B fp32 in HBM, converted to bf16 during LDS staging.
// tile 128x128, BK=64, 256 threads = 4 waves (2x2 of 64x64), 16x16x32 MFMA.
// LDS: As[row][k] / Bs[n][k] bf16, XOR-swizzled 16B slots: slot = (k>>3) ^ (r&7).
template<int ACT, bool ADD>
__device__ __forceinline__ void gemm_core(
    const float* __restrict__ A, int lda,
    const float* __restrict__ B, int ldb,
    const float* __restrict__ bias,
    float* __restrict__ C, int ldc,
    int M, int N, int K, int bm, int bn)
{
    __shared__ char lds[32768];
    char* As  = lds;            // 128 rows * 128 B
    char* Bsm = lds + 16384;    // 128 n    * 128 B

    const int tid  = threadIdx.x;
    const int lane = tid & 63;
    const int wave = tid >> 6;
    const int wm = (wave >> 1) * 64;
    const int wn = (wave & 1) * 64;

    f32x4 acc[4][4];
    #pragma unroll
    for (int i = 0; i < 4; ++i)
        #pragma unroll
        for (int j = 0; j < 4; ++j)
            acc[i][j] = (f32x4){0.f,0.f,0.f,0.f};

    const int arow  = tid >> 4;        // 0..15 (+16r)
    const int akcol = (tid & 15) * 4;  // 0..60
    const int bkp   = (tid >> 5) * 2;  // 0..14 even (+16r)
    const int bncol = (tid & 31) * 4;  // 0..124
    const int rot   = (lane >> 1) & 3;

    for (int k0 = 0; k0 < K; k0 += 64) {
        // ---- stage A: [128 rows][64 k] ----
        #pragma unroll
        for (int r = 0; r < 8; ++r) {
            int row = arow + r*16;
            float4 v = make_float4(0.f,0.f,0.f,0.f);
            if (bm + row < M && k0 + akcol < K)
                v = *(const float4*)(A + (size_t)(bm + row)*lda + k0 + akcol);
            unsigned int u0 = pack2bf(v.x, v.y);
            unsigned int u1 = pack2bf(v.z, v.w);
            int off = row*128 + (((akcol >> 3) ^ (row & 7)) << 4) + (akcol & 7)*2;
            *(uint2*)(As + off) = make_uint2(u0, u1);
        }
        // ---- stage B transposed: [128 n][64 k] ----
        #pragma unroll
        for (int r = 0; r < 4; ++r) {
            int k = bkp + r*16;
            float4 va = make_float4(0.f,0.f,0.f,0.f), vb = va;
            if ((k0 + k) < K && (bn + bncol) < N) {
                va = *(const float4*)(B + (size_t)(k0 + k    )*ldb + bn + bncol);
                vb = *(const float4*)(B + (size_t)(k0 + k + 1)*ldb + bn + bncol);
            }
            float fa[4] = {va.x, va.y, va.z, va.w};
            float fb[4] = {vb.x, vb.y, vb.z, vb.w};
            #pragma unroll
            for (int jj = 0; jj < 4; ++jj) {
                int j = (jj + rot) & 3;
                int n = bncol + j;
                unsigned int u = pack2bf(fa[j], fb[j]);
                int off = n*128 + (((k >> 3) ^ (n & 7)) << 4) + (k & 7)*2;
                *(unsigned int*)(Bsm + off) = u;
            }
        }
        __syncthreads();
        // ---- MFMA ----
        #pragma unroll
        for (int kk = 0; kk < 2; ++kk) {
            bf16x8 af[4], bfr[4];
            int ks = kk*4 + (lane >> 4);   // k>>3
            #pragma unroll
            for (int mi = 0; mi < 4; ++mi) {
                int row = wm + mi*16 + (lane & 15);
                af[mi] = *(const bf16x8*)(As + row*128 + ((ks ^ (row & 7)) << 4));
            }
            #pragma unroll
            for (int ni = 0; ni < 4; ++ni) {
                int n = wn + ni*16 + (lane & 15);
                bfr[ni] = *(const bf16x8*)(Bsm + n*128 + ((ks ^ (n & 7)) << 4));
            }
            #pragma unroll
            for (int mi = 0; mi < 4; ++mi)
                #pragma unroll
                for (int ni = 0; ni < 4; ++ni)
                    acc[mi][ni] = __builtin_amdgcn_mfma_f32_16x16x32_bf16(
                        af[mi], bfr[ni], acc[mi][ni], 0, 0, 0);
        }
        __syncthreads();
    }

    // ---- epilogue: D[row=(l>>4)*4+r][col=l&15] ----
    const int rbase = (lane >> 4) * 4;
    const int cbase = lane & 15;
    #pragma unroll
    for (int mi = 0; mi < 4; ++mi) {
        #pragma unroll
        for (int r = 0; r < 4; ++r) {
            int row = bm + wm + mi*16 + rbase + r;
            if (row >= M) continue;
            #pragma unroll
            for (int ni = 0; ni < 4; ++ni) {
                int col = bn + wn + ni*16 + cbase;
                if (col >= N) continue;
                float v = acc[mi][ni][r];
                if (bias) v += bias[col];
                if (ACT == ACT_SILU)     v = siluf(v);
                if (ACT == ACT_GELU)     v = geluf(v);
                if (ACT == ACT_SOFTPLUS) v = softplusf(v);
                if (ADD) C[(size_t)row*ldc + col] += v;
                else     C[(size_t)row*ldc + col]  = v;
            }
        }
    }
}

template<int ACT, bool ADD>
__global__ __launch_bounds__(256) void gemm_mfma_k(
    const float* __restrict__ A, int lda,
    const float* __restrict__ B, int ldb,
    const float* __restrict__ bias,
    float* __restrict__ C, int ldc,
    int M, int N, int K)
{
    gemm_core<ACT,ADD>(A,lda,B,ldb,bias,C,ldc,M,N,K, blockIdx.y*128, blockIdx.x*128);
}

// fused QKV: z selects weight/bias/output (params renamed to avoid C0 macro clash)
__global__ __launch_bounds__(256) void gemm_qkv_k(
    const float* __restrict__ A, int lda,
    const float* __restrict__ Bq, const float* __restrict__ Bk, const float* __restrict__ Bv,
    const float* __restrict__ biq, const float* __restrict__ bik, const float* __restrict__ biv,
    float* __restrict__ Cq, float* __restrict__ Ck, float* __restrict__ Cv,
    int ldbc, int M, int N, int K)
{
    const float* B  = (blockIdx.z == 0) ? Bq  : (blockIdx.z == 1) ? Bk  : Bv;
    const float* bi = (blockIdx.z == 0) ? biq : (blockIdx.z == 1) ? bik : biv;
    float*       C  = (blockIdx.z == 0) ? Cq  : (blockIdx.z == 1) ? Ck  : Cv;
    gemm_core<ACT_NONE,false>(A,lda,B,ldbc,bi,C,ldbc,M,N,K, blockIdx.y*128, blockIdx.x*128);
}

static void gemm(hipStream_t st, const float* A, int lda, const float* B, int ldb,
                 const float* bias, float* C, int ldc, int M, int N, int K,
                 int act, bool add)
{
    dim3 g((N + 127)/128, (M + 127)/128), b(256);
    if (add) { gemm_mfma_k<ACT_NONE,true><<<g,b,0,st>>>(A,lda,B,ldb,bias,C,ldc,M,N,K); return; }
    switch (act) {
      case ACT_SILU:     gemm_mfma_k<ACT_SILU,false><<<g,b,0,st>>>(A,lda,B,ldb,bias,C,ldc,M,N,K); break;
      case ACT_GELU:     gemm_mfma_k<ACT_GELU,false><<<g,b,0,st>>>(A,lda,B,ldb,bias,C,ldc,M,N,K); break;
      case ACT_SOFTPLUS: gemm_mfma_k<ACT_SOFTPLUS,false><<<g,b,0,st>>>(A,lda,B,ldb,bias,C,ldc,M,N,K); break;
      default:           gemm_mfma_k<ACT_NONE,false><<<g,b,0,st>>>(A,lda,B,ldb,bias,C,ldc,M,N,K); break;
    }
}

// ---------------- small kernels ----------------

__global__ void tsemb_k(const int* __restrict__ t, float* __restrict__ o){
    int b = blockIdx.x, j = threadIdx.x;           // block 640
    float f = expf(-9.210340371976184f * (float)j / 640.f);
    float a = (float)t[b] * f;
    o[b*DM + j]       = cosf(a);
    o[b*DM + 640 + j] = sinf(a);
}

__global__ void silu_v(const float* __restrict__ a, float* __restrict__ o, int n){
    int i = blockIdx.x*256 + threadIdx.x; if (i < n) o[i] = siluf(a[i]);
}
__global__ void copy_v(const float* __restrict__ a, float* __restrict__ o, int n){
    int i = blockIdx.x*256 + threadIdx.x; if (i < n) o[i] = a[i];
}
__global__ void add_v(const float* __restrict__ a, float* __restrict__ o, int n){
    int i = blockIdx.x*256 + threadIdx.x; if (i < n) o[i] += a[i];
}

__global__ void embed_k(const float* __restrict__ x, const float* __restrict__ seq_emb,
                        const float* __restrict__ eW, const float* __restrict__ eb,
                        float* __restrict__ h){
    int i = blockIdx.x;            // b*600 + t*30 + vo
    int c = threadIdx.x;           // 64
    int vo = i % 30; int bt = i / 30; int t = bt % 20; int b = bt / 20;
    int v = d_VORDER[vo];
    const float* xp = x + (size_t)(b*20 + t)*48 + v*3;
    float val = eb[c] + seq_emb[(size_t)(t*16 + v)*64 + c]
              + xp[0]*eW[c] + xp[1]*eW[64 + c] + xp[2]*eW[128 + c];
    h[(size_t)i*64 + c] = val;
}

__global__ void h2hm_k(const float* __restrict__ h, float* __restrict__ hm){
    int row = blockIdx.x;          // b*30+v
    int b = row / 30, v = row % 30;
    for (int idx = threadIdx.x; idx < DM; idx += 256) {
        int t = idx >> 6, c = idx & 63;
        hm[(size_t)row*DM + idx] = h[((size_t)(b*20 + t)*30 + v)*64 + c];
    }
}
__global__ void hm2ht_k(const float* __restrict__ hm, float* __restrict__ ht){
    int row = blockIdx.x;          // b*20+t
    int b = row / 20, t = row % 20;
    for (int idx = threadIdx.x; idx < DTR_; idx += 256) {
        int v = idx >> 6, c = idx & 63;
        ht[(size_t)row*DTR_ + idx] = hm[((size_t)(b*30 + v))*DM + t*64 + c];
    }
}

__global__ void rms_k(const float* __restrict__ x, const float* __restrict__ w,
                      const float* __restrict__ addv, int addDiv,
                      float* __restrict__ o, int D){
    int row = blockIdx.x;
    const float* xr = x + (size_t)row*D;
    float ss = 0.f;
    for (int i = threadIdx.x; i < D; i += 256){ float v = xr[i]; ss += v*v; }
    ss = blockReduceSum(ss);
    float rs = rsqrtf(ss/(float)D + 1e-5f);
    const float* ap = addv ? addv + (size_t)(row/addDiv)*D : nullptr;
    for (int i = threadIdx.x; i < D; i += 256){
        float v = xr[i]*rs*w[i];
        if (ap) v += ap[i];
        o[(size_t)row*D + i] = v;
    }
}

__global__ void ln_k(const float* __restrict__ x, const float* __restrict__ w,
                     const float* __restrict__ b, float* __restrict__ o, int D){
    int row = blockIdx.x;
    const float* xr = x + (size_t)row*D;
    float s1 = 0.f, s2 = 0.f;
    for (int i = threadIdx.x; i < D; i += 256){ float v = xr[i]; s1 += v; s2 += v*v; }
    s1 = blockReduceSum(s1);
    s2 = blockReduceSum(s2);
    float m = s1/(float)D, var = s2/(float)D - m*m, rs = rsqrtf(var + 1e-5f);
    for (int i = threadIdx.x; i < D; i += 256)
        o[(size_t)row*D + i] = (xr[i] - m)*rs*w[i] + b[i];
}

__global__ void convsilu_k(const float* __restrict__ xz, const float* __restrict__ cw,
                           const float* __restrict__ cb, float* __restrict__ xc){
    int idx = blockIdx.x*256 + threadIdx.x;
    if (idx >= NB*NV*DI) return;
    int d = idx % DI; int bl = idx / DI; int l = bl % NV; int b = bl / NV;
    float acc = cb[d];
    #pragma unroll
    for (int k = 0; k < 4; ++k) {
        int ls = l - 3 + k;
        if (ls >= 0) acc += xz[((size_t)(b*NV + ls))*(2*DI) + d] * cw[d*4 + k];
    }
    xc[idx] = siluf(acc);
}

__global__ __launch_bounds__(256) void scan_k(
    const float* __restrict__ delta, const float* __restrict__ dbc,
    const float* __restrict__ xc, const float* __restrict__ xz,
    const float* __restrict__ A_log, const float* __restrict__ Dp,
    float* __restrict__ y2)
{
    __shared__ float sBC[30][32];
    int b = blockIdx.x / 10;
    int dblk = blockIdx.x % 10;
    int tid = threadIdx.x;
    for (int i = tid; i < 30*32; i += 256) {
        int l = i >> 5, j = i & 31;
        sBC[l][j] = dbc[((size_t)(b*NV + l))*112 + 80 + j];
    }
    __syncthreads();
    int d = dblk*256 + tid;
    float aA[16], s[16];
    #pragma unroll
    for (int n = 0; n < 16; ++n){ aA[n] = -expf(A_log[(size_t)d*16 + n]); s[n] = 0.f; }
    float dpv = Dp[d];
    for (int l = 0; l < NV; ++l) {
        size_t base = (size_t)(b*NV + l);
        float dv   = delta[base*DI + d];
        float xcv  = xc[base*DI + d];
        float resv = xz[base*(2*DI) + DI + d];
        float y = 0.f;
        #pragma unroll
        for (int n = 0; n < 16; ++n) {
            float dA = expf(dv*aA[n]);
            s[n] = dA*s[n] + dv*sBC[l][n]*xcv;
            y = fmaf(s[n], sBC[l][16 + n], y);
        }
        y2[base*DI + d] = (y + xcv*dpv) * siluf(resv);
    }
}

__global__ __launch_bounds__(64) void attn_k(const float* __restrict__ q,
                                             const float* __restrict__ k,
                                             const float* __restrict__ v,
                                             float* __restrict__ o){
    int idx = blockIdx.x;          // b*160 + t*8 + h
    int h = idx % 8; int bt = idx / 8; int t = bt % 20; int b = bt / 20;
    int lane = threadIdx.x;
    const float* qp = q + ((size_t)(b*20 + t))*DTR_ + h*DH;
    float qr[4];
    #pragma unroll
    for (int i = 0; i < 4; ++i){ int j = lane + i*64; qr[i] = (j < DH) ? qp[j] : 0.f; }
    __shared__ float sc[20];
    const float scale = 0.06454972243679028f;  // 1/sqrt(240)
    for (int s2 = 0; s2 < 20; ++s2) {
        const float* kp = k + ((size_t)(b*20 + s2))*DTR_ + h*DH;
        float p = 0.f;
        #pragma unroll
        for (int i = 0; i < 4; ++i){ int j = lane + i*64; if (j < DH) p = fmaf(qr[i], kp[j], p); }
        #pragma unroll
        for (int off = 32; off > 0; off >>= 1) p += __shfl_down(p, off, 64);
        if (lane == 0) sc[s2] = p*scale;
    }
    __syncthreads();
    float m = -1e30f;
    #pragma unroll
    for (int s2 = 0; s2 < 20; ++s2) m = fmaxf(m, sc[s2]);
    float ps[20]; float sum = 0.f;
    #pragma unroll
    for (int s2 = 0; s2 < 20; ++s2){ ps[s2] = expf(sc[s2] - m); sum += ps[s2]; }
    float inv = 1.f/sum;
    float acc[4] = {0.f,0.f,0.f,0.f};
    for (int s2 = 0; s2 < 20; ++s2) {
        const float* vp = v + ((size_t)(b*20 + s2))*DTR_ + h*DH;
        float w2 = ps[s2]*inv;
        #pragma unroll
        for (int i = 0; i < 4; ++i){ int j = lane + i*64; if (j < DH) acc[i] = fmaf(w2, vp[j], acc[i]); }
    }
    float* op = o + ((size_t)(b*20 + t))*DTR_ + h*DH;
    #pragma unroll
    for (int i = 0; i < 4; ++i){ int j = lane + i*64; if (j < DH) op[j] = acc[i]; }
}

__global__ void sty_ln_k(const float* __restrict__ x, const float* __restrict__ lw,
                         const float* __restrict__ lb, const float* __restrict__ ss,
                         float* __restrict__ o){
    int row = blockIdx.x;          // b*20+t
    int b = row / 20;
    const float* xr = x + (size_t)row*DTR_;
    float s1 = 0.f, s2 = 0.f;
    for (int i = threadIdx.x; i < DTR_; i += 256){ float v = xr[i]; s1 += v; s2 += v*v; }
    s1 = blockReduceSum(s1);
    s2 = blockReduceSum(s2);
    float m = s1/(float)DTR_, var = s2/(float)DTR_ - m*m, rs = rsqrtf(var + 1e-5f);
    const float* sb = ss + (size_t)b*(2*DTR_);
    for (int i = threadIdx.x; i < DTR_; i += 256) {
        float v = (xr[i] - m)*rs*lw[i] + lb[i];
        v = v*(1.f + sb[i]) + sb[DTR_ + i];
        o[(size_t)row*DTR_ + i] = siluf(v);
    }
}

__global__ void head_k(const float* __restrict__ fr, const float* __restrict__ W,
                       const float* __restrict__ bias, float* __restrict__ out){
    int row = blockIdx.x;          // b*20+t
    int tid = threadIdx.x;         // 48
    int v = tid/3, j = tid%3;
    const float* g = fr + (size_t)row*DTR_ + d_REV[v]*64;
    float acc = bias[j];
    #pragma unroll
    for (int c = 0; c < 64; ++c) acc = fmaf(g[c], W[c*3 + j], acc);
    out[(size_t)row*48 + tid] = acc;
}

// ---------------- orchestration ----------------
extern "C" void kernel_launch(void* const* d_in, const int* in_sizes, int n_in,
                              void* d_out, int out_size, void* d_ws, size_t ws_size,
                              hipStream_t stream)
{
    const float* x        = (const float*)d_in[0];
    const int*   tst      = (const int*)  d_in[1];
    const float* seq_emb  = (const float*)d_in[2];
    const float* emb_W    = (const float*)d_in[3];
    const float* emb_b    = (const float*)d_in[4];
    const float* time_W1  = (const float*)d_in[5];
    const float* time_b1  = (const float*)d_in[6];
    const float* time_W2  = (const float*)d_in[7];
    const float* time_b2  = (const float*)d_in[8];
    const float* m_norm_w = (const float*)d_in[9];
    const float* m_emb_W  = (const float*)d_in[10];
    const float* m_emb_b  = (const float*)d_in[11];
    const float* m_in_W   = (const float*)d_in[12];
    const float* m_conv_w = (const float*)d_in[13];
    const float* m_conv_b = (const float*)d_in[14];
    const float* m_xproj_W= (const float*)d_in[15];
    const float* m_dt_W   = (const float*)d_in[16];
    const float* m_dt_b   = (const float*)d_in[17];
    const float* m_A_log  = (const float*)d_in[18];
    const float* m_D      = (const float*)d_in[19];
    const float* m_out_W  = (const float*)d_in[20];
    const float* t_ln1_w  = (const float*)d_in[21];
    const float* t_ln1_b  = (const float*)d_in[22];
    const float* t_Wq     = (const float*)d_in[23];
    const float* t_bq     = (const float*)d_in[24];
    const float* t_Wk     = (const float*)d_in[25];
    const float* t_bk     = (const float*)d_in[26];
    const float* t_Wv     = (const float*)d_in[27];
    const float* t_bv     = (const float*)d_in[28];
    const float* t_s1_eW  = (const float*)d_in[29];
    const float* t_s1_eb  = (const float*)d_in[30];
    const float* t_s1_lw  = (const float*)d_in[31];
    const float* t_s1_lb  = (const float*)d_in[32];
    const float* t_s1_oW  = (const float*)d_in[33];
    const float* t_s1_ob  = (const float*)d_in[34];
    const float* t_ln2_w  = (const float*)d_in[35];
    const float* t_ln2_b  = (const float*)d_in[36];
    const float* t_fW1    = (const float*)d_in[37];
    const float* t_fb1    = (const float*)d_in[38];
    const float* t_fW2    = (const float*)d_in[39];
    const float* t_fb2    = (const float*)d_in[40];
    const float* t_s2_eW  = (const float*)d_in[41];
    const float* t_s2_eb  = (const float*)d_in[42];
    const float* t_s2_lw  = (const float*)d_in[43];
    const float* t_s2_lb  = (const float*)d_in[44];
    const float* t_s2_oW  = (const float*)d_in[45];
    const float* t_s2_ob  = (const float*)d_in[46];
    const float* normf_w  = (const float*)d_in[47];
    const float* head_W   = (const float*)d_in[48];
    const float* head_b   = (const float*)d_in[49];

    float* ws = (float*)d_ws;
    size_t off = 0;
    auto alloc = [&](size_t n){ float* p = ws + off; off += n; return p; };

    const size_t HSZ = (size_t)NB*NT*NV*C0;   // 1,228,800
    float* embt = alloc((size_t)NB*DM);
    float* emb1 = alloc((size_t)NB*TEMPD);
    float* emb  = alloc((size_t)NB*TEMPD);
    float* semb = alloc((size_t)NB*TEMPD);
    float* h    = alloc(HSZ);
    float* pre0 = alloc(HSZ);
    float* pre1 = alloc(HSZ);
    float* hm   = alloc(HSZ);
    float* hn   = alloc(HSZ);
    float* memb = alloc((size_t)NB*DM);
    float* xz   = alloc((size_t)NB*NV*2*DI);
    float* xcb  = alloc((size_t)NB*NV*DI);
    float* dbc  = alloc((size_t)NB*NV*112);
    float* delta= alloc((size_t)NB*NV*DI);
    float* y2   = alloc((size_t)NB*NV*DI);
    float* xn   = alloc(HSZ);
    float* qb   = alloc(HSZ);
    float* kb   = alloc(HSZ);
    float* vb   = alloc(HSZ);
    float* aty  = alloc(HSZ);
    float* sty  = alloc(HSZ);
    float* ssb  = alloc((size_t)NB*2*DTR_);
    float* mid  = alloc((size_t)NB*NT*2560);
    (void)ws_size; (void)in_sizes; (void)n_in; (void)out_size;

    // ---- time embedding + MLP ----
    tsemb_k<<<NB, 640, 0, stream>>>(tst, embt);
    gemm(stream, embt, DM, time_W1, TEMPD, time_b1, emb1, TEMPD, NB, TEMPD, DM, ACT_SILU, false);
    gemm(stream, emb1, TEMPD, time_W2, TEMPD, time_b2, emb, TEMPD, NB, TEMPD, TEMPD, ACT_NONE, false);
    silu_v<<<(NB*TEMPD + 255)/256, 256, 0, stream>>>(emb, semb, NB*TEMPD);

    // ---- vertex embedding + VORDER gather ----
    embed_k<<<NB*NT*NV, 64, 0, stream>>>(x, seq_emb, emb_W, emb_b, h);

    for (int i = 0; i < 4; ++i) {
        if (i == 0) copy_v<<<(int)((HSZ + 255)/256), 256, 0, stream>>>(h, pre0, (int)HSZ);
        if (i == 1) copy_v<<<(int)((HSZ + 255)/256), 256, 0, stream>>>(h, pre1, (int)HSZ);

        // ---- mamba half ----
        gemm(stream, emb, TEMPD, m_emb_W + (size_t)i*TEMPD*DM, DM, m_emb_b + (size_t)i*DM,
             memb, DM, NB, DM, TEMPD, ACT_NONE, false);
        h2hm_k<<<NB*NV, 256, 0, stream>>>(h, hm);
        rms_k<<<NB*NV, 256, 0, stream>>>(hm, m_norm_w + (size_t)i*DM, memb, NV, hn, DM);
        gemm(stream, hn, DM, m_in_W + (size_t)i*DM*2*DI, 2*DI, nullptr,
             xz, 2*DI, NB*NV, 2*DI, DM, ACT_NONE, false);
        convsilu_k<<<(NB*NV*DI + 255)/256, 256, 0, stream>>>(
            xz, m_conv_w + (size_t)i*DI*4, m_conv_b + (size_t)i*DI, xcb);
        gemm(stream, xcb, DI, m_xproj_W + (size_t)i*DI*112, 112, nullptr,
             dbc, 112, NB*NV, 112, DI, ACT_NONE, false);
        gemm(stream, dbc, 112, m_dt_W + (size_t)i*DTRANK*DI, DI, m_dt_b + (size_t)i*DI,
             delta, DI, NB*NV, DI, DTRANK, ACT_SOFTPLUS, false);
        scan_k<<<NB*10, 256, 0, stream>>>(delta, dbc, xcb, xz,
             m_A_log + (size_t)i*DI*DSTATE, m_D + (size_t)i*DI, y2);
        gemm(stream, y2, DI, m_out_W + (size_t)i*DI*DM, DM, nullptr,
             hm, DM, NB*NV, DM, DI, ACT_NONE, true /*hm += mamba_out*/);
        hm2ht_k<<<NB*NT, 256, 0, stream>>>(hm, h);   // h now holds ht (b,t,1920)

        // ---- transformer half ----
        ln_k<<<NB*NT, 256, 0, stream>>>(h, t_ln1_w + (size_t)i*DTR_, t_ln1_b + (size_t)i*DTR_, xn, DTR_);
        {
            dim3 g((DTR_ + 127)/128, (NB*NT + 127)/128, 3), b(256);
            gemm_qkv_k<<<g, b, 0, stream>>>(xn, DTR_,
                t_Wq + (size_t)i*DTR_*DTR_, t_Wk + (size_t)i*DTR_*DTR_, t_Wv + (size_t)i*DTR_*DTR_,
                t_bq + (size_t)i*DTR_, t_bk + (size_t)i*DTR_, t_bv + (size_t)i*DTR_,
                qb, kb, vb, DTR_, NB*NT, DTR_, DTR_);
        }
        attn_k<<<NB*NT*NHEAD_, 64, 0, stream>>>(qb, kb, vb, aty);

        // stylize 1
        gemm(stream, semb, TEMPD, t_s1_eW + (size_t)i*TEMPD*2*DTR_, 2*DTR_, t_s1_eb + (size_t)i*2*DTR_,
             ssb, 2*DTR_, NB, 2*DTR_, TEMPD, ACT_NONE, false);
        sty_ln_k<<<NB*NT, 256, 0, stream>>>(aty, t_s1_lw + (size_t)i*DTR_, t_s1_lb + (size_t)i*DTR_, ssb, sty);
        gemm(stream, sty, DTR_, t_s1_oW + (size_t)i*DTR_*DTR_, DTR_, t_s1_ob + (size_t)i*DTR_,
             h, DTR_, NB*NT, DTR_, DTR_, ACT_NONE, true);

        // FFN
        ln_k<<<NB*NT, 256, 0, stream>>>(h, t_ln2_w + (size_t)i*DTR_, t_ln2_b + (size_t)i*DTR_, xn, DTR_);
        gemm(stream, xn, DTR_, t_fW1 + (size_t)i*DTR_*2560, 2560, t_fb1 + (size_t)i*2560,
             mid, 2560, NB*NT, 2560, DTR_, ACT_GELU, false);
        gemm(stream, mid, 2560, t_fW2 + (size_t)i*2560*DTR_, DTR_, t_fb2 + (size_t)i*DTR_,
             aty, DTR_, NB*NT, DTR_, 2560, ACT_NONE, false);

        // stylize 2
        gemm(stream, semb, TEMPD, t_s2_eW + (size_t)i*TEMPD*2*DTR_, 2*DTR_, t_s2_eb + (size_t)i*2*DTR_,
             ssb, 2*DTR_, NB, 2*DTR_, TEMPD, ACT_NONE, false);
        sty_ln_k<<<NB*NT, 256, 0, stream>>>(aty, t_s2_lw + (size_t)i*DTR_, t_s2_lb + (size_t)i*DTR_, ssb, sty);
        gemm(stream, sty, DTR_, t_s2_oW + (size_t)i*DTR_*DTR_, DTR_, t_s2_ob + (size_t)i*DTR_,
             h, DTR_, NB*NT, DTR_, DTR_, ACT_NONE, true);

        // skip connections
        if (i == 2) add_v<<<(int)((HSZ + 255)/256), 256, 0, stream>>>(pre1, h, (int)HSZ);
        if (i == 3) add_v<<<(int)((HSZ + 255)/256), 256, 0, stream>>>(pre0, h, (int)HSZ);
    }

    // final rmsnorm + REV gather + head
    rms_k<<<NB*NT, 256, 0, stream>>>(h, normf_w, nullptr, 1, xn, DTR_);
    head_k<<<NB*NT, 48, 0, stream>>>(xn, head_W, head_b, (float*)d_out);
}

// Round 4
// 3698.986 us; speedup vs baseline: 2.1873x; 2.0079x over previous
//
#include <hip/hip_runtime.h>
#include <hip/hip_bf16.h>
#include <math.h>

// ---------------- constants ----------------
#define NB 32     // batch
#define NT 20     // time steps
#define NV 30     // gathered vertices (VORDER length)
#define C0 64     // per-vertex channels (JLD)
#define DM 1280   // D_MAMB = 20*64
#define DTR_ 1920 // D_TRANS = 30*64
#define DI 2560   // D_INNER
#define DSTATE 16
#define DTRANK 80
#define TEMPD 512
#define NHEAD_ 8
#define DH 240

__constant__ int d_VORDER[30] = {9,8,7,10,11,12,11,10,7,13,14,15,14,13,7,6,0,1,2,1,0,6,3,4,5,4,3,6,7,8};
__constant__ int d_REV[16]    = {20,19,18,26,25,24,27,28,29,0,7,6,5,13,12,11};

typedef __bf16 bf16x8 __attribute__((ext_vector_type(8)));
typedef float f32x4  __attribute__((ext_vector_type(4)));

__device__ __forceinline__ float siluf(float x){ return x / (1.f + expf(-x)); }
__device__ __forceinline__ float geluf(float x){
    float x3 = x*x*x;
    return 0.5f*x*(1.f + tanhf(0.7978845608028654f*(x + 0.044715f*x3)));
}
__device__ __forceinline__ float softplusf(float x){
    return fmaxf(x, 0.f) + log1pf(expf(-fabsf(x)));
}

__device__ __forceinline__ unsigned int pack2bf(float x, float y){
    __bf16 a = (__bf16)x, b = (__bf16)y;
    unsigned short ua = __builtin_bit_cast(unsigned short, a);
    unsigned short ub = __builtin_bit_cast(unsigned short, b);
    return (unsigned int)ua | ((unsigned int)ub << 16);
}

// block-wide sum, blockDim.x == 256 (4 waves)
__device__ __forceinline__ float blockReduceSum(float v){
    #pragma unroll
    for (int off = 32; off > 0; off >>= 1) v += __shfl_down(v, off, 64);
    __shared__ float sred[4];
    __shared__ float stot;
    int w = threadIdx.x >> 6;
    if ((threadIdx.x & 63) == 0) sred[w] = v;
    __syncthreads();
    if (threadIdx.x == 0) stot = sred[0] + sred[1] + sred[2] + sred[3];
    __syncthreads();
    return stot;
}

enum { ACT_NONE=0, ACT_SILU=1, ACT_GELU=2, ACT_SOFTPLUS=3 };

// ---------------- MFMA bf16 GEMM core (double-buffered) ----------------
// C[M,N](ldc) = act(A[M,K](lda) @ B[K,N](ldb) + bias) [+= if ADD]
// A,B fp32 in HBM -> bf16 in LDS. Tile BM x 128, BK=64. 256 threads = 2x2 waves.
// Wave tile (BM/2) x 64; frags MI=BM/32 x NI=4 of 16x16x32.
// LDS XOR swizzle per 16B slot: slot = (k>>3) ^ (row&7).
// Pipeline: load regs(t+1) -> barrier -> compute LDS[cur] -> write LDS[cur^1].
template<int BM, int ACT, bool ADD>
__device__ __forceinline__ void gemm_core(
    const float* __restrict__ A, int lda,
    const float* __restrict__ B, int ldb,
    const float* __restrict__ bias,
    float* __restrict__ C, int ldc,
    int M, int N, int K, int bm, int bn)
{
    constexpr int BN   = 128;
    constexpr int MI   = BM / 32;      // A-frags per wave
    constexpr int NI   = 4;            // B-frags per wave
    constexpr int AREG = BM / 16;      // float4 A-loads per thread
    constexpr int BPASS= 4;            // B passes (2 float4 each)
    constexpr int HALF = (BM + BN) * 128;

    __shared__ char lds[2 * HALF];

    const int tid  = threadIdx.x;
    const int lane = tid & 63;
    const int wave = tid >> 6;
    const int wm = (wave >> 1) * (BM/2);
    const int wn = (wave & 1) * 64;

    f32x4 acc[MI][NI];
    #pragma unroll
    for (int i = 0; i < MI; ++i)
        #pragma unroll
        for (int j = 0; j < NI; ++j)
            acc[i][j] = (f32x4){0.f,0.f,0.f,0.f};

    const int arow = tid >> 4;          // 0..15
    const int akc  = (tid & 15) * 4;    // 0..60
    const int bkp  = (tid >> 5) * 2;    // 0..14 even
    const int bnc  = (tid & 31) * 4;    // 0..124
    const int rot  = (lane >> 1) & 3;

    float4 avr[AREG];
    float4 bvr[BPASS][2];

    const int nkt = (K + 63) / 64;

    auto loadTile = [&](int k0){
        #pragma unroll
        for (int i = 0; i < AREG; ++i) {
            int row = arow + i*16;
            float4 v = make_float4(0.f,0.f,0.f,0.f);
            if (bm + row < M && k0 + akc < K)
                v = *(const float4*)(A + (size_t)(bm + row)*lda + k0 + akc);
            avr[i] = v;
        }
        #pragma unroll
        for (int p = 0; p < BPASS; ++p) {
            int k = bkp + p*16;
            float4 va = make_float4(0.f,0.f,0.f,0.f), vb = va;
            if ((k0 + k) < K && (bn + bnc) < N) {
                va = *(const float4*)(B + (size_t)(k0 + k    )*ldb + bn + bnc);
                vb = *(const float4*)(B + (size_t)(k0 + k + 1)*ldb + bn + bnc);
            }
            bvr[p][0] = va; bvr[p][1] = vb;
        }
    };
    auto writeTile = [&](int buf){
        char* As  = lds + buf*HALF;
        char* Bsm = lds + buf*HALF + BM*128;
        #pragma unroll
        for (int i = 0; i < AREG; ++i) {
            int row = arow + i*16;
            unsigned int u0 = pack2bf(avr[i].x, avr[i].y);
            unsigned int u1 = pack2bf(avr[i].z, avr[i].w);
            int off = row*128 + (((akc >> 3) ^ (row & 7)) << 4) + (akc & 7)*2;
            *(uint2*)(As + off) = make_uint2(u0, u1);
        }
        #pragma unroll
        for (int p = 0; p < BPASS; ++p) {
            int k = bkp + p*16;
            float fa[4] = {bvr[p][0].x, bvr[p][0].y, bvr[p][0].z, bvr[p][0].w};
            float fb[4] = {bvr[p][1].x, bvr[p][1].y, bvr[p][1].z, bvr[p][1].w};
            #pragma unroll
            for (int jj = 0; jj < 4; ++jj) {
                int j = (jj + rot) & 3;
                int n = bnc + j;
                unsigned int u = pack2bf(fa[j], fb[j]);
                int off = n*128 + (((k >> 3) ^ (n & 7)) << 4) + (k & 7)*2;
                *(unsigned int*)(Bsm + off) = u;
            }
        }
    };
    auto computeTile = [&](int buf){
        char* As  = lds + buf*HALF;
        char* Bsm = lds + buf*HALF + BM*128;
        #pragma unroll
        for (int kk = 0; kk < 2; ++kk) {
            bf16x8 af[MI], bfr[NI];
            int ks = kk*4 + (lane >> 4);   // k>>3
            #pragma unroll
            for (int mi = 0; mi < MI; ++mi) {
                int row = wm + mi*16 + (lane & 15);
                af[mi] = *(const bf16x8*)(As + row*128 + ((ks ^ (row & 7)) << 4));
            }
            #pragma unroll
            for (int ni = 0; ni < NI; ++ni) {
                int n = wn + ni*16 + (lane & 15);
                bfr[ni] = *(const bf16x8*)(Bsm + n*128 + ((ks ^ (n & 7)) << 4));
            }
            #pragma unroll
            for (int mi = 0; mi < MI; ++mi)
                #pragma unroll
                for (int ni = 0; ni < NI; ++ni)
                    acc[mi][ni] = __builtin_amdgcn_mfma_f32_16x16x32_bf16(
                        af[mi], bfr[ni], acc[mi][ni], 0, 0, 0);
        }
    };

    // prologue
    loadTile(0);
    writeTile(0);
    int cur = 0;
    for (int t = 0; t < nkt; ++t) {
        bool more = (t + 1 < nkt);
        if (more) loadTile((t + 1) * 64);   // global loads in flight over compute
        __syncthreads();                    // LDS[cur] ready for all waves
        computeTile(cur);
        if (more) writeTile(cur ^ 1);       // vvmcnt wait inserted by compiler
        cur ^= 1;
    }

    // ---- epilogue: D[row=(l>>4)*4+r][col=l&15] ----
    const int rbase = (lane >> 4) * 4;
    const int cbase = lane & 15;
    #pragma unroll
    for (int mi = 0; mi < MI; ++mi) {
        #pragma unroll
        for (int r = 0; r < 4; ++r) {
            int row = bm + wm + mi*16 + rbase + r;
            if (row >= M) continue;
            #pragma unroll
            for (int ni = 0; ni < NI; ++ni) {
                int col = bn + wn + ni*16 + cbase;
                if (col >= N) continue;
                float v = acc[mi][ni][r];
                if (bias) v += bias[col];
                if (ACT == ACT_SILU)     v = siluf(v);
                if (ACT == ACT_GELU)     v = geluf(v);
                if (ACT == ACT_SOFTPLUS) v = softplusf(v);
                if (ADD) C[(size_t)row*ldc + col] += v;
                else     C[(size_t)row*ldc + col]  = v;
            }
        }
    }
}

template<int BM, int ACT, bool ADD>
__global__ __launch_bounds__(256) void gemm_mfma_k(
    const float* __restrict__ A, int lda,
    const float* __restrict__ B, int ldb,
    const float* __restrict__ bias,
    float* __restrict__ C, int ldc,
    int M, int N, int K)
{
    gemm_core<BM,ACT,ADD>(A,lda,B,ldb,bias,C,ldc,M,N,K, blockIdx.y*BM, blockIdx.x*128);
}

// fused QKV: z selects weight/bias/output
__global__ __launch_bounds__(256) void gemm_qkv_k(
    const float* __restrict__ A, int lda,
    const float* __restrict__ Bq, const float* __restrict__ Bk, const float* __restrict__ Bv,
    const float* __restrict__ biq, const float* __restrict__ bik, const float* __restrict__ biv,
    float* __restrict__ Cq, float* __restrict__ Ck, float* __restrict__ Cv,
    int ldbc, int M, int N, int K)
{
    const float* B  = (blockIdx.z == 0) ? Bq  : (blockIdx.z == 1) ? Bk  : Bv;
    const float* bi = (blockIdx.z == 0) ? biq : (blockIdx.z == 1) ? bik : biv;
    float*       C  = (blockIdx.z == 0) ? Cq  : (blockIdx.z == 1) ? Ck  : Cv;
    gemm_core<64,ACT_NONE,false>(A,lda,B,ldbc,bi,C,ldbc,M,N,K, blockIdx.y*64, blockIdx.x*128);
}

// batched memb: z = layer; M=NB, N=DM, K=TEMPD
__global__ __launch_bounds__(256) void gemm_memb_k(
    const float* __restrict__ A, const float* __restrict__ W,
    const float* __restrict__ bias, float* __restrict__ Cc)
{
    int z = blockIdx.z;
    gemm_core<32,ACT_NONE,false>(A, TEMPD, W + (size_t)z*TEMPD*DM, DM,
        bias + (size_t)z*DM, Cc + (size_t)z*NB*DM, DM,
        NB, DM, TEMPD, blockIdx.y*32, blockIdx.x*128);
}

// batched stylize-emb: z in [0,8): z<4 -> s1 layer z ; z>=4 -> s2 layer z-4. M=NB, N=2*DTR_, K=TEMPD
__global__ __launch_bounds__(256) void gemm_ssb_k(
    const float* __restrict__ A,
    const float* __restrict__ W1, const float* __restrict__ W2,
    const float* __restrict__ b1, const float* __restrict__ b2,
    float* __restrict__ Cc)
{
    int z = blockIdx.z; int l = z & 3;
    const float* W  = ((z < 4) ? W1 : W2) + (size_t)l*TEMPD*2*DTR_;
    const float* bb = ((z < 4) ? b1 : b2) + (size_t)l*2*DTR_;
    gemm_core<32,ACT_NONE,false>(A, TEMPD, W, 2*DTR_, bb,
        Cc + (size_t)z*NB*2*DTR_, 2*DTR_,
        NB, 2*DTR_, TEMPD, blockIdx.y*32, blockIdx.x*128);
}

static void gemm(hipStream_t st, const float* A, int lda, const float* B, int ldb,
                 const float* bias, float* C, int ldc, int M, int N, int K,
                 int act, bool add, int bmSel)
{
    dim3 b(256);
    if (bmSel == 32) {
        dim3 g((N + 127)/128, (M + 31)/32);
        if (act == ACT_SILU) gemm_mfma_k<32,ACT_SILU,false><<<g,b,0,st>>>(A,lda,B,ldb,bias,C,ldc,M,N,K);
        else                 gemm_mfma_k<32,ACT_NONE,false><<<g,b,0,st>>>(A,lda,B,ldb,bias,C,ldc,M,N,K);
        return;
    }
    dim3 g((N + 127)/128, (M + 63)/64);
    if (add) { gemm_mfma_k<64,ACT_NONE,true><<<g,b,0,st>>>(A,lda,B,ldb,bias,C,ldc,M,N,K); return; }
    switch (act) {
      case ACT_GELU:     gemm_mfma_k<64,ACT_GELU,false><<<g,b,0,st>>>(A,lda,B,ldb,bias,C,ldc,M,N,K); break;
      case ACT_SOFTPLUS: gemm_mfma_k<64,ACT_SOFTPLUS,false><<<g,b,0,st>>>(A,lda,B,ldb,bias,C,ldc,M,N,K); break;
      default:           gemm_mfma_k<64,ACT_NONE,false><<<g,b,0,st>>>(A,lda,B,ldb,bias,C,ldc,M,N,K); break;
    }
}

// ---------------- small kernels ----------------

__global__ void tsemb_k(const int* __restrict__ t, float* __restrict__ o){
    int b = blockIdx.x, j = threadIdx.x;           // block 640
    float f = expf(-9.210340371976184f * (float)j / 640.f);
    float a = (float)t[b] * f;
    o[b*DM + j]       = cosf(a);
    o[b*DM + 640 + j] = sinf(a);
}

__global__ void silu_v(const float* __restrict__ a, float* __restrict__ o, int n){
    int i = blockIdx.x*256 + threadIdx.x; if (i < n) o[i] = siluf(a[i]);
}
__global__ void copy_v(const float* __restrict__ a, float* __restrict__ o, int n){
    int i = blockIdx.x*256 + threadIdx.x; if (i < n) o[i] = a[i];
}
__global__ void add_v(const float* __restrict__ a, float* __restrict__ o, int n){
    int i = blockIdx.x*256 + threadIdx.x; if (i < n) o[i] += a[i];
}

__global__ void embed_k(const float* __restrict__ x, const float* __restrict__ seq_emb,
                        const float* __restrict__ eW, const float* __restrict__ eb,
                        float* __restrict__ h){
    int i = blockIdx.x;            // b*600 + t*30 + vo
    int c = threadIdx.x;           // 64
    int vo = i % 30; int bt = i / 30; int t = bt % 20; int b = bt / 20;
    int v = d_VORDER[vo];
    const float* xp = x + (size_t)(b*20 + t)*48 + v*3;
    float val = eb[c] + seq_emb[(size_t)(t*16 + v)*64 + c]
              + xp[0]*eW[c] + xp[1]*eW[64 + c] + xp[2]*eW[128 + c];
    h[(size_t)i*64 + c] = val;
}

__global__ void h2hm_k(const float* __restrict__ h, float* __restrict__ hm){
    int row = blockIdx.x;          // b*30+v
    int b = row / 30, v = row % 30;
    for (int idx = threadIdx.x; idx < DM; idx += 256) {
        int t = idx >> 6, c = idx & 63;
        hm[(size_t)row*DM + idx] = h[((size_t)(b*20 + t)*30 + v)*64 + c];
    }
}
__global__ void hm2ht_k(const float* __restrict__ hm, float* __restrict__ ht){
    int row = blockIdx.x;          // b*20+t
    int b = row / 20, t = row % 20;
    for (int idx = threadIdx.x; idx < DTR_; idx += 256) {
        int v = idx >> 6, c = idx & 63;
        ht[(size_t)row*DTR_ + idx] = hm[((size_t)(b*30 + v))*DM + t*64 + c];
    }
}

__global__ void rms_k(const float* __restrict__ x, const float* __restrict__ w,
                      const float* __restrict__ addv, int addDiv,
                      float* __restrict__ o, int D){
    int row = blockIdx.x;
    const float* xr = x + (size_t)row*D;
    float ss = 0.f;
    for (int i = threadIdx.x; i < D; i += 256){ float v = xr[i]; ss += v*v; }
    ss = blockReduceSum(ss);
    float rs = rsqrtf(ss/(float)D + 1e-5f);
    const float* ap = addv ? addv + (size_t)(row/addDiv)*D : nullptr;
    for (int i = threadIdx.x; i < D; i += 256){
        float v = xr[i]*rs*w[i];
        if (ap) v += ap[i];
        o[(size_t)row*D + i] = v;
    }
}

__global__ void ln_k(const float* __restrict__ x, const float* __restrict__ w,
                     const float* __restrict__ b, float* __restrict__ o, int D){
    int row = blockIdx.x;
    const float* xr = x + (size_t)row*D;
    float s1 = 0.f, s2 = 0.f;
    for (int i = threadIdx.x; i < D; i += 256){ float v = xr[i]; s1 += v; s2 += v*v; }
    s1 = blockReduceSum(s1);
    s2 = blockReduceSum(s2);
    float m = s1/(float)D, var = s2/(float)D - m*m, rs = rsqrtf(var + 1e-5f);
    for (int i = threadIdx.x; i < D; i += 256)
        o[(size_t)row*D + i] = (xr[i] - m)*rs*w[i] + b[i];
}

__global__ void convsilu_k(const float* __restrict__ xz, const float* __restrict__ cw,
                           const float* __restrict__ cb, float* __restrict__ xc){
    int idx = blockIdx.x*256 + threadIdx.x;
    if (idx >= NB*NV*DI) return;
    int d = idx % DI; int bl = idx / DI; int l = bl % NV; int b = bl / NV;
    float acc = cb[d];
    #pragma unroll
    for (int k = 0; k < 4; ++k) {
        int ls = l - 3 + k;
        if (ls >= 0) acc += xz[((size_t)(b*NV + ls))*(2*DI) + d] * cw[d*4 + k];
    }
    xc[idx] = siluf(acc);
}

__global__ __launch_bounds__(256) void scan_k(
    const float* __restrict__ delta, const float* __restrict__ dbc,
    const float* __restrict__ xc, const float* __restrict__ xz,
    const float* __restrict__ A_log, const float* __restrict__ Dp,
    float* __restrict__ y2)
{
    __shared__ float sBC[30][32];
    int b = blockIdx.x / 10;
    int dblk = blockIdx.x % 10;
    int tid = threadIdx.x;
    for (int i = tid; i < 30*32; i += 256) {
        int l = i >> 5, j = i & 31;
        sBC[l][j] = dbc[((size_t)(b*NV + l))*112 + 80 + j];
    }
    __syncthreads();
    int d = dblk*256 + tid;
    float aA[16], s[16];
    #pragma unroll
    for (int n = 0; n < 16; ++n){ aA[n] = -expf(A_log[(size_t)d*16 + n]); s[n] = 0.f; }
    float dpv = Dp[d];
    for (int l = 0; l < NV; ++l) {
        size_t base = (size_t)(b*NV + l);
        float dv   = delta[base*DI + d];
        float xcv  = xc[base*DI + d];
        float resv = xz[base*(2*DI) + DI + d];
        float y = 0.f;
        #pragma unroll
        for (int n = 0; n < 16; ++n) {
            float dA = expf(dv*aA[n]);
            s[n] = dA*s[n] + dv*sBC[l][n]*xcv;
            y = fmaf(s[n], sBC[l][16 + n], y);
        }
        y2[base*DI + d] = (y + xcv*dpv) * siluf(resv);
    }
}

__global__ __launch_bounds__(64) void attn_k(const float* __restrict__ q,
                                             const float* __restrict__ k,
                                             const float* __restrict__ v,
                                             float* __restrict__ o){
    int idx = blockIdx.x;          // b*160 + t*8 + h
    int h = idx % 8; int bt = idx / 8; int t = bt % 20; int b = bt / 20;
    int lane = threadIdx.x;
    const float* qp = q + ((size_t)(b*20 + t))*DTR_ + h*DH;
    float qr[4];
    #pragma unroll
    for (int i = 0; i < 4; ++i){ int j = lane + i*64; qr[i] = (j < DH) ? qp[j] : 0.f; }
    __shared__ float sc[20];
    const float scale = 0.06454972243679028f;  // 1/sqrt(240)
    for (int s2 = 0; s2 < 20; ++s2) {
        const float* kp = k + ((size_t)(b*20 + s2))*DTR_ + h*DH;
        float p = 0.f;
        #pragma unroll
        for (int i = 0; i < 4; ++i){ int j = lane + i*64; if (j < DH) p = fmaf(qr[i], kp[j], p); }
        #pragma unroll
        for (int off = 32; off > 0; off >>= 1) p += __shfl_down(p, off, 64);
        if (lane == 0) sc[s2] = p*scale;
    }
    __syncthreads();
    float m = -1e30f;
    #pragma unroll
    for (int s2 = 0; s2 < 20; ++s2) m = fmaxf(m, sc[s2]);
    float ps[20]; float sum = 0.f;
    #pragma unroll
    for (int s2 = 0; s2 < 20; ++s2){ ps[s2] = expf(sc[s2] - m); sum += ps[s2]; }
    float inv = 1.f/sum;
    float acc[4] = {0.f,0.f,0.f,0.f};
    for (int s2 = 0; s2 < 20; ++s2) {
        const float* vp = v + ((size_t)(b*20 + s2))*DTR_ + h*DH;
        float w2 = ps[s2]*inv;
        #pragma unroll
        for (int i = 0; i < 4; ++i){ int j = lane + i*64; if (j < DH) acc[i] = fmaf(w2, vp[j], acc[i]); }
    }
    float* op = o + ((size_t)(b*20 + t))*DTR_ + h*DH;
    #pragma unroll
    for (int i = 0; i < 4; ++i){ int j = lane + i*64; if (j < DH) op[j] = acc[i]; }
}

__global__ void sty_ln_k(const float* __restrict__ x, const float* __restrict__ lw,
                         const float* __restrict__ lb, const float* __restrict__ ss,
                         float* __restrict__ o){
    int row = blockIdx.x;          // b*20+t
    int b = row / 20;
    const float* xr = x + (size_t)row*DTR_;
    float s1 = 0.f, s2 = 0.f;
    for (int i = threadIdx.x; i < DTR_; i += 256){ float v = xr[i]; s1 += v; s2 += v*v; }
    s1 = blockReduceSum(s1);
    s2 = blockReduceSum(s2);
    float m = s1/(float)DTR_, var = s2/(float)DTR_ - m*m, rs = rsqrtf(var + 1e-5f);
    const float* sb = ss + (size_t)b*(2*DTR_);
    for (int i = threadIdx.x; i < DTR_; i += 256) {
        float v = (xr[i] - m)*rs*lw[i] + lb[i];
        v = v*(1.f + sb[i]) + sb[DTR_ + i];
        o[(size_t)row*DTR_ + i] = siluf(v);
    }
}

__global__ void head_k(const float* __restrict__ fr, const float* __restrict__ W,
                       const float* __restrict__ bias, float* __restrict__ out){
    int row = blockIdx.x;          // b*20+t
    int tid = threadIdx.x;         // 48
    int v = tid/3, j = tid%3;
    const float* g = fr + (size_t)row*DTR_ + d_REV[v]*64;
    float acc = bias[j];
    #pragma unroll
    for (int c = 0; c < 64; ++c) acc = fmaf(g[c], W[c*3 + j], acc);
    out[(size_t)row*48 + tid] = acc;
}

// ---------------- orchestration ----------------
extern "C" void kernel_launch(void* const* d_in, const int* in_sizes, int n_in,
                              void* d_out, int out_size, void* d_ws, size_t ws_size,
                              hipStream_t stream)
{
    const float* x        = (const float*)d_in[0];
    const int*   tst      = (const int*)  d_in[1];
    const float* seq_emb  = (const float*)d_in[2];
    const float* emb_W    = (const float*)d_in[3];
    const float* emb_b    = (const float*)d_in[4];
    const float* time_W1  = (const float*)d_in[5];
    const float* time_b1  = (const float*)d_in[6];
    const float* time_W2  = (const float*)d_in[7];
    const float* time_b2  = (const float*)d_in[8];
    const float* m_norm_w = (const float*)d_in[9];
    const float* m_emb_W  = (const float*)d_in[10];
    const float* m_emb_b  = (const float*)d_in[11];
    const float* m_in_W   = (const float*)d_in[12];
    const float* m_conv_w = (const float*)d_in[13];
    const float* m_conv_b = (const float*)d_in[14];
    const float* m_xproj_W= (const float*)d_in[15];
    const float* m_dt_W   = (const float*)d_in[16];
    const float* m_dt_b   = (const float*)d_in[17];
    const float* m_A_log  = (const float*)d_in[18];
    const float* m_D      = (const float*)d_in[19];
    const float* m_out_W  = (const float*)d_in[20];
    const float* t_ln1_w  = (const float*)d_in[21];
    const float* t_ln1_b  = (const float*)d_in[22];
    const float* t_Wq     = (const float*)d_in[23];
    const float* t_bq     = (const float*)d_in[24];
    const float* t_Wk     = (const float*)d_in[25];
    const float* t_bk     = (const float*)d_in[26];
    const float* t_Wv     = (const float*)d_in[27];
    const float* t_bv     = (const float*)d_in[28];
    const float* t_s1_eW  = (const float*)d_in[29];
    const float* t_s1_eb  = (const float*)d_in[30];
    const float* t_s1_lw  = (const float*)d_in[31];
    const float* t_s1_lb  = (const float*)d_in[32];
    const float* t_s1_oW  = (const float*)d_in[33];
    const float* t_s1_ob  = (const float*)d_in[34];
    const float* t_ln2_w  = (const float*)d_in[35];
    const float* t_ln2_b  = (const float*)d_in[36];
    const float* t_fW1    = (const float*)d_in[37];
    const float* t_fb1    = (const float*)d_in[38];
    const float* t_fW2    = (const float*)d_in[39];
    const float* t_fb2    = (const float*)d_in[40];
    const float* t_s2_eW  = (const float*)d_in[41];
    const float* t_s2_eb  = (const float*)d_in[42];
    const float* t_s2_lw  = (const float*)d_in[43];
    const float* t_s2_lb  = (const float*)d_in[44];
    const float* t_s2_oW  = (const float*)d_in[45];
    const float* t_s2_ob  = (const float*)d_in[46];
    const float* normf_w  = (const float*)d_in[47];
    const float* head_W   = (const float*)d_in[48];
    const float* head_b   = (const float*)d_in[49];

    float* ws = (float*)d_ws;
    size_t off = 0;
    auto alloc = [&](size_t n){ float* p = ws + off; off += n; return p; };

    const size_t HSZ = (size_t)NB*NT*NV*C0;   // 1,228,800
    float* embt = alloc((size_t)NB*DM);
    float* emb1 = alloc((size_t)NB*TEMPD);
    float* emb  = alloc((size_t)NB*TEMPD);
    float* semb = alloc((size_t)NB*TEMPD);
    float* h    = alloc(HSZ);
    float* pre0 = alloc(HSZ);
    float* pre1 = alloc(HSZ);
    float* hm   = alloc(HSZ);
    float* hn   = alloc(HSZ);
    float* memb4= alloc((size_t)4*NB*DM);
    float* ssb8 = alloc((size_t)8*NB*2*DTR_);
    float* xz   = alloc((size_t)NB*NV*2*DI);
    float* xcb  = alloc((size_t)NB*NV*DI);
    float* dbc  = alloc((size_t)NB*NV*112);
    float* delta= alloc((size_t)NB*NV*DI);
    float* y2   = alloc((size_t)NB*NV*DI);
    float* xn   = alloc(HSZ);
    float* qb   = alloc(HSZ);
    float* kb   = alloc(HSZ);
    float* vb   = alloc(HSZ);
    float* aty  = alloc(HSZ);
    float* sty  = alloc(HSZ);
    float* mid  = alloc((size_t)NB*NT*2560);
    (void)ws_size; (void)in_sizes; (void)n_in; (void)out_size;

    // ---- time embedding + MLP ----
    tsemb_k<<<NB, 640, 0, stream>>>(tst, embt);
    gemm(stream, embt, DM, time_W1, TEMPD, time_b1, emb1, TEMPD, NB, TEMPD, DM, ACT_SILU, false, 32);
    gemm(stream, emb1, TEMPD, time_W2, TEMPD, time_b2, emb, TEMPD, NB, TEMPD, TEMPD, ACT_NONE, false, 32);
    silu_v<<<(NB*TEMPD + 255)/256, 256, 0, stream>>>(emb, semb, NB*TEMPD);

    // ---- hoisted per-layer emb projections (batched over layers) ----
    {
        dim3 g1(DM/128, 1, 4), b(256);
        gemm_memb_k<<<g1, b, 0, stream>>>(emb, m_emb_W, m_emb_b, memb4);
        dim3 g2((2*DTR_)/128, 1, 8);
        gemm_ssb_k<<<g2, b, 0, stream>>>(semb, t_s1_eW, t_s2_eW, t_s1_eb, t_s2_eb, ssb8);
    }

    // ---- vertex embedding + VORDER gather ----
    embed_k<<<NB*NT*NV, 64, 0, stream>>>(x, seq_emb, emb_W, emb_b, h);

    for (int i = 0; i < 4; ++i) {
        if (i == 0) copy_v<<<(int)((HSZ + 255)/256), 256, 0, stream>>>(h, pre0, (int)HSZ);
        if (i == 1) copy_v<<<(int)((HSZ + 255)/256), 256, 0, stream>>>(h, pre1, (int)HSZ);

        // ---- mamba half ----
        h2hm_k<<<NB*NV, 256, 0, stream>>>(h, hm);
        rms_k<<<NB*NV, 256, 0, stream>>>(hm, m_norm_w + (size_t)i*DM, memb4 + (size_t)i*NB*DM, NV, hn, DM);
        gemm(stream, hn, DM, m_in_W + (size_t)i*DM*2*DI, 2*DI, nullptr,
             xz, 2*DI, NB*NV, 2*DI, DM, ACT_NONE, false, 64);
        convsilu_k<<<(NB*NV*DI + 255)/256, 256, 0, stream>>>(
            xz, m_conv_w + (size_t)i*DI*4, m_conv_b + (size_t)i*DI, xcb);
        gemm(stream, xcb, DI, m_xproj_W + (size_t)i*DI*112, 112, nullptr,
             dbc, 112, NB*NV, 112, DI, ACT_NONE, false, 32);
        gemm(stream, dbc, 112, m_dt_W + (size_t)i*DTRANK*DI, DI, m_dt_b + (size_t)i*DI,
             delta, DI, NB*NV, DI, DTRANK, ACT_SOFTPLUS, false, 64);
        scan_k<<<NB*10, 256, 0, stream>>>(delta, dbc, xcb, xz,
             m_A_log + (size_t)i*DI*DSTATE, m_D + (size_t)i*DI, y2);
        gemm(stream, y2, DI, m_out_W + (size_t)i*DI*DM, DM, nullptr,
             hm, DM, NB*NV, DM, DI, ACT_NONE, true, 64);
        hm2ht_k<<<NB*NT, 256, 0, stream>>>(hm, h);   // h now holds ht (b,t,1920)

        // ---- transformer half ----
        ln_k<<<NB*NT, 256, 0, stream>>>(h, t_ln1_w + (size_t)i*DTR_, t_ln1_b + (size_t)i*DTR_, xn, DTR_);
        {
            dim3 g(DTR_/128, (NB*NT + 63)/64, 3), b(256);
            gemm_qkv_k<<<g, b, 0, stream>>>(xn, DTR_,
                t_Wq + (size_t)i*DTR_*DTR_, t_Wk + (size_t)i*DTR_*DTR_, t_Wv + (size_t)i*DTR_*DTR_,
                t_bq + (size_t)i*DTR_, t_bk + (size_t)i*DTR_, t_bv + (size_t)i*DTR_,
                qb, kb, vb, DTR_, NB*NT, DTR_, DTR_);
        }
        attn_k<<<NB*NT*NHEAD_, 64, 0, stream>>>(qb, kb, vb, aty);

        // stylize 1
        sty_ln_k<<<NB*NT, 256, 0, stream>>>(aty, t_s1_lw + (size_t)i*DTR_, t_s1_lb + (size_t)i*DTR_,
                                            ssb8 + (size_t)i*NB*2*DTR_, sty);
        gemm(stream, sty, DTR_, t_s1_oW + (size_t)i*DTR_*DTR_, DTR_, t_s1_ob + (size_t)i*DTR_,
             h, DTR_, NB*NT, DTR_, DTR_, ACT_NONE, true, 64);

        // FFN
        ln_k<<<NB*NT, 256, 0, stream>>>(h, t_ln2_w + (size_t)i*DTR_, t_ln2_b + (size_t)i*DTR_, xn, DTR_);
        gemm(stream, xn, DTR_, t_fW1 + (size_t)i*DTR_*2560, 2560, t_fb1 + (size_t)i*2560,
             mid, 2560, NB*NT, 2560, DTR_, ACT_GELU, false, 64);
        gemm(stream, mid, 2560, t_fW2 + (size_t)i*2560*DTR_, DTR_, t_fb2 + (size_t)i*DTR_,
             aty, DTR_, NB*NT, DTR_, 2560, ACT_NONE, false, 64);

        // stylize 2
        sty_ln_k<<<NB*NT, 256, 0, stream>>>(aty, t_s2_lw + (size_t)i*DTR_, t_s2_lb + (size_t)i*DTR_,
                                            ssb8 + (size_t)(4 + i)*NB*2*DTR_, sty);
        gemm(stream, sty, DTR_, t_s2_oW + (size_t)i*DTR_*DTR_, DTR_, t_s2_ob + (size_t)i*DTR_,
             h, DTR_, NB*NT, DTR_, DTR_, ACT_NONE, true, 64);

        // skip connections
        if (i == 2) add_v<<<(int)((HSZ + 255)/256), 256, 0, stream>>>(pre1, h, (int)HSZ);
        if (i == 3) add_v<<<(int)((HSZ + 255)/256), 256, 0, stream>>>(pre0, h, (int)HSZ);
    }

    // final rmsnorm + REV gather + head
    rms_k<<<NB*NT, 256, 0, stream>>>(h, normf_w, nullptr, 1, xn, DTR_);
    head_k<<<NB*NT, 48, 0, stream>>>(xn, head_W, head_b, (float*)d_out);
}

// Round 5
// 1892.677 us; speedup vs baseline: 4.2748x; 1.9544x over previous
//
#include <hip/hip_runtime.h>
#include <hip/hip_bf16.h>
#include <math.h>

// ---------------- constants ----------------
#define NB 32
#define NT 20
#define NV 30
#define JLD 64
#define DM 1280
#define DTR_ 1920
#define DI 2560
#define DSTATE 16
#define DTRANK 80
#define TEMPD 512
#define NHEAD_ 8
#define DH 240

__constant__ int d_VORDER[30] = {9,8,7,10,11,12,11,10,7,13,14,15,14,13,7,6,0,1,2,1,0,6,3,4,5,4,3,6,7,8};
__constant__ int d_REV[16]    = {20,19,18,26,25,24,27,28,29,0,7,6,5,13,12,11};

typedef unsigned short u16;
typedef __bf16 bf16x8 __attribute__((ext_vector_type(8)));
typedef float f32x4  __attribute__((ext_vector_type(4)));

__device__ __forceinline__ float siluf(float x){ return x / (1.f + expf(-x)); }
__device__ __forceinline__ float geluf(float x){
    float x3 = x*x*x;
    return 0.5f*x*(1.f + tanhf(0.7978845608028654f*(x + 0.044715f*x3)));
}
__device__ __forceinline__ float softplusf(float x){
    return fmaxf(x, 0.f) + log1pf(expf(-fabsf(x)));
}
__device__ __forceinline__ u16 bfbits(float x){
    return __builtin_bit_cast(u16, (__bf16)x);
}

// async global(16B) -> LDS
__device__ __forceinline__ void gload16(const void* g, void* l){
    __builtin_amdgcn_global_load_lds(
        (const __attribute__((address_space(1))) void*)g,
        (__attribute__((address_space(3))) void*)l, 16, 0, 0);
}

__device__ __forceinline__ float blockReduceSum(float v){
    #pragma unroll
    for (int off = 32; off > 0; off >>= 1) v += __shfl_down(v, off, 64);
    __shared__ float sred[4];
    __shared__ float stot;
    int w = threadIdx.x >> 6;
    if ((threadIdx.x & 63) == 0) sred[w] = v;
    __syncthreads();
    if (threadIdx.x == 0) stot = sred[0] + sred[1] + sred[2] + sred[3];
    __syncthreads();
    return stot;
}

enum { ACT_NONE=0, ACT_SILU=1, ACT_GELU=2, ACT_SOFTPLUS=3 };
// MODE: 0 = store f32, 1 = += f32, 2 = atomicAdd f32, 3 = store f32 + bf16, 4 = store bf16 only

// ---------------- bf16 MFMA GEMM, global_load_lds + counted vmcnt ----------------
// A bf16 [M, lda] row-major (lda = padded K); B bf16 [N, ldb] (pre-transposed, ldb = padded K).
// Tile BM x 128, BK = 64, 256 threads = 2x2 waves. LDS XOR-swizzled 16B slots.
template<int BM, int ACT, int MODE>
__device__ __forceinline__ void gemm_dev(
    const u16* __restrict__ A, int lda,
    const u16* __restrict__ B, int ldb,
    const float* __restrict__ bias,
    float* __restrict__ C, int ldc,
    u16* __restrict__ Cbf, int ldcb,
    int M, int N, int KT, int bm, int bn, int ktb)
{
    constexpr int HALF = (BM + 128) * 128;       // bytes / buffer
    constexpr int L    = (BM + 128) * 8 / 256;   // gload16 per thread per stage (5 or 6)
    constexpr int MI   = BM / 32;

    __shared__ char lds[2 * HALF];

    const int tid = threadIdx.x, lane = tid & 63, wv = tid >> 6;
    const int wm = (wv >> 1) * (BM / 2), wn = (wv & 1) * 64;

    f32x4 acc[MI][4];
    #pragma unroll
    for (int i = 0; i < MI; ++i)
        #pragma unroll
        for (int j = 0; j < 4; ++j) acc[i][j] = (f32x4){0.f,0.f,0.f,0.f};

    auto stage = [&](int buf, int kt){
        const int kofs = kt * 64;
        #pragma unroll
        for (int i = 0; i < L; ++i) {
            int gb = i*256 + wv*64;          // wave-uniform granule base
            int g  = gb + lane;
            const u16* src;
            if (i*256 < BM*8) {              // A region (region boundary aligns to 256)
                int row = g >> 3, slot = g & 7;
                src = A + (size_t)(bm + row)*lda + kofs + ((slot ^ (row & 7)) << 3);
            } else {
                int g2 = g - BM*8;
                int row = g2 >> 3, slot = g2 & 7;
                src = B + (size_t)(bn + row)*ldb + kofs + ((slot ^ (row & 7)) << 3);
            }
            gload16(src, lds + buf*HALF + gb*16);
        }
    };
    auto compute = [&](int buf){
        const char* Ab = lds + buf*HALF;
        const char* Bb = Ab + BM*128;
        #pragma unroll
        for (int kk = 0; kk < 2; ++kk) {
            int ks = kk*4 + (lane >> 4);
            bf16x8 af[MI], bfr[4];
            #pragma unroll
            for (int mi = 0; mi < MI; ++mi) {
                int row = wm + mi*16 + (lane & 15);
                af[mi] = *(const bf16x8*)(Ab + row*128 + ((ks ^ (row & 7)) << 4));
            }
            #pragma unroll
            for (int ni = 0; ni < 4; ++ni) {
                int n = wn + ni*16 + (lane & 15);
                bfr[ni] = *(const bf16x8*)(Bb + n*128 + ((ks ^ (n & 7)) << 4));
            }
            #pragma unroll
            for (int mi = 0; mi < MI; ++mi)
                #pragma unroll
                for (int ni = 0; ni < 4; ++ni)
                    acc[mi][ni] = __builtin_amdgcn_mfma_f32_16x16x32_bf16(
                        af[mi], bfr[ni], acc[mi][ni], 0, 0, 0);
        }
    };

    stage(0, ktb);
    int cur = 0;
    for (int t = 0; t < KT; ++t) {
        if (t + 1 < KT) {
            stage(cur ^ 1, ktb + t + 1);
            if constexpr (BM == 32) asm volatile("s_waitcnt vmcnt(5)" ::: "memory");
            else                    asm volatile("s_waitcnt vmcnt(6)" ::: "memory");
        } else {
            asm volatile("s_waitcnt vmcnt(0)" ::: "memory");
        }
        __builtin_amdgcn_sched_barrier(0);
        __builtin_amdgcn_s_barrier();
        __builtin_amdgcn_sched_barrier(0);
        compute(cur);
        __builtin_amdgcn_sched_barrier(0);
        __builtin_amdgcn_s_barrier();
        __builtin_amdgcn_sched_barrier(0);
        cur ^= 1;
    }

    const int rb = (lane >> 4) * 4, cb = lane & 15;
    #pragma unroll
    for (int mi = 0; mi < MI; ++mi) {
        #pragma unroll
        for (int r = 0; r < 4; ++r) {
            int row = bm + wm + mi*16 + rb + r;
            #pragma unroll
            for (int ni = 0; ni < 4; ++ni) {
                int col = bn + wn + ni*16 + cb;
                if (col >= N) continue;
                float v = acc[mi][ni][r];
                if (bias) v += bias[col];
                if (ACT == ACT_SILU)     v = siluf(v);
                if (ACT == ACT_GELU)     v = geluf(v);
                if (ACT == ACT_SOFTPLUS) v = softplusf(v);
                if (MODE == 1)      C[(size_t)row*ldc + col] += v;
                else if (MODE == 2) atomicAdd(&C[(size_t)row*ldc + col], v);
                else {
                    if (MODE != 4) C[(size_t)row*ldc + col] = v;
                    if (MODE >= 3) Cbf[(size_t)row*ldcb + col] = bfbits(v);
                }
            }
        }
    }
    (void)M;
}

template<int BM, int ACT, int MODE>
__global__ __launch_bounds__(256) void gemm_g_bk(
    const u16* __restrict__ A, int lda, const u16* __restrict__ B, int ldb,
    const float* __restrict__ bias, float* __restrict__ C, int ldc,
    u16* __restrict__ Cbf, int ldcb, int M, int N, int KT)
{
    gemm_dev<BM,ACT,MODE>(A,lda,B,ldb,bias,C,ldc,Cbf,ldcb,M,N,KT,
                          blockIdx.y*BM, blockIdx.x*128, blockIdx.z*KT);
}

// QKV: z selects weight slice (contiguous Wq|Wk|Wv in slab) / bias / output
__global__ __launch_bounds__(256) void gemm_qkv_bk(
    const u16* __restrict__ A, const u16* __restrict__ Wqkv,
    const float* __restrict__ bq, const float* __restrict__ bk2, const float* __restrict__ bv,
    float* __restrict__ oq, float* __restrict__ ok2, float* __restrict__ ov)
{
    int z = blockIdx.z;
    const float* bb = (z == 0) ? bq : (z == 1) ? bk2 : bv;
    float*       cc = (z == 0) ? oq : (z == 1) ? ok2 : ov;
    gemm_dev<32,ACT_NONE,0>(A, DTR_, Wqkv + (size_t)z*DTR_*DTR_, DTR_, bb,
                            cc, DTR_, nullptr, 0, NB*NT, DTR_, 30,
                            blockIdx.y*32, blockIdx.x*128, 0);
}

// memb: z = layer
__global__ __launch_bounds__(256) void gemm_memb_bk(
    const u16* __restrict__ A, const u16* __restrict__ W,
    const float* __restrict__ bias, float* __restrict__ Cc)
{
    int z = blockIdx.z;
    gemm_dev<32,ACT_NONE,0>(A, TEMPD, W + (size_t)z*DM*TEMPD, TEMPD, bias + (size_t)z*DM,
                            Cc + (size_t)z*NB*DM, DM, nullptr, 0, NB, DM, 8,
                            blockIdx.y*32, blockIdx.x*128, 0);
}

// ssb: z in [0,8): z<4 s1 layer z, else s2 layer z-4; W contiguous 8 slices
__global__ __launch_bounds__(256) void gemm_ssb_bk(
    const u16* __restrict__ A, const u16* __restrict__ W,
    const float* __restrict__ b1, const float* __restrict__ b2, float* __restrict__ Cc)
{
    int z = blockIdx.z;
    const float* bb = (z < 4) ? b1 + (size_t)z*2*DTR_ : b2 + (size_t)(z-4)*2*DTR_;
    gemm_dev<32,ACT_NONE,0>(A, TEMPD, W + (size_t)z*2*DTR_*TEMPD, TEMPD, bb,
                            Cc + (size_t)z*NB*2*DTR_, 2*DTR_, nullptr, 0, NB, 2*DTR_, 8,
                            blockIdx.y*32, blockIdx.x*128, 0);
}

// ---------------- weight transpose+convert: fp32[K,N] -> bf16[Np,Kp], zero-padded ----------------
struct ConvEnt { const float* src; u16* dst; int K, N, Kp, Np, tile0; };
struct ConvTab { ConvEnt e[14]; int n; };

__global__ __launch_bounds__(256) void wconv_k(ConvTab tab){
    int t = blockIdx.x;
    int i = 0;
    while (i + 1 < tab.n && tab.e[i+1].tile0 <= t) ++i;
    const float* src = tab.e[i].src;
    u16* dst = tab.e[i].dst;
    const int K = tab.e[i].K, N = tab.e[i].N, Kp = tab.e[i].Kp, Np = tab.e[i].Np;
    int lt = t - tab.e[i].tile0;
    int nx = Np >> 6;
    int n0 = (lt % nx) << 6, k0 = (lt / nx) << 6;

    __shared__ u16 tile[64][72];
    const int tid = threadIdx.x;
    {
        int r = tid >> 2, cs = (tid & 3) << 4;
        int gk = k0 + r;
        #pragma unroll
        for (int j = 0; j < 16; j += 4) {
            int gn = n0 + cs + j;
            float4 v = make_float4(0.f,0.f,0.f,0.f);
            if (gk < K) {
                if (gn + 3 < N) v = *(const float4*)(src + (size_t)gk*N + gn);
                else {
                    float tmp[4] = {0.f,0.f,0.f,0.f};
                    for (int e2 = 0; e2 < 4; ++e2) if (gn + e2 < N) tmp[e2] = src[(size_t)gk*N + gn + e2];
                    v = make_float4(tmp[0],tmp[1],tmp[2],tmp[3]);
                }
            }
            tile[r][cs+j+0] = bfbits(v.x);
            tile[r][cs+j+1] = bfbits(v.y);
            tile[r][cs+j+2] = bfbits(v.z);
            tile[r][cs+j+3] = bfbits(v.w);
        }
    }
    __syncthreads();
    {
        int n = tid >> 2, ks = (tid & 3) << 4;
        u16 outv[16];
        #pragma unroll
        for (int j = 0; j < 16; ++j) outv[j] = tile[ks + j][n];
        u16* dp = dst + (size_t)(n0 + n)*Kp + k0 + ks;
        *(uint4*)dp       = *(uint4*)&outv[0];
        *(uint4*)(dp + 8) = *(uint4*)&outv[8];
    }
}

// ---------------- small kernels ----------------

__global__ void tsemb_k(const int* __restrict__ t, u16* __restrict__ o){
    int b = blockIdx.x, j = threadIdx.x;   // 640
    float f = expf(-9.210340371976184f * (float)j / 640.f);
    float a = (float)t[b] * f;
    o[b*DM + j]       = bfbits(cosf(a));
    o[b*DM + 640 + j] = bfbits(sinf(a));
}

__global__ void silu_bf_v(const float* __restrict__ a, u16* __restrict__ o, int n){
    int i = blockIdx.x*256 + threadIdx.x; if (i < n) o[i] = bfbits(siluf(a[i]));
}
__global__ void copy_v(const float* __restrict__ a, float* __restrict__ o, int n){
    int i = blockIdx.x*256 + threadIdx.x; if (i < n) o[i] = a[i];
}
__global__ void add_v(const float* __restrict__ a, float* __restrict__ o, int n){
    int i = blockIdx.x*256 + threadIdx.x; if (i < n) o[i] += a[i];
}
__global__ void zero_k(float* __restrict__ p, int n){
    int i = blockIdx.x*256 + threadIdx.x; if (i < n) p[i] = 0.f;
}

__global__ void embed_k(const float* __restrict__ x, const float* __restrict__ seq_emb,
                        const float* __restrict__ eW, const float* __restrict__ eb,
                        float* __restrict__ h){
    int i = blockIdx.x;            // b*600 + t*30 + vo
    int c = threadIdx.x;           // 64
    int vo = i % 30; int bt = i / 30; int t = bt % 20; int b = bt / 20;
    int v = d_VORDER[vo];
    const float* xp = x + (size_t)(b*20 + t)*48 + v*3;
    float val = eb[c] + seq_emb[(size_t)(t*16 + v)*64 + c]
              + xp[0]*eW[c] + xp[1]*eW[64 + c] + xp[2]*eW[128 + c];
    h[(size_t)i*64 + c] = val;
}

__global__ void h2hm_k(const float* __restrict__ h, float* __restrict__ hm){
    int row = blockIdx.x;          // b*30+v
    int b = row / 30, v = row % 30;
    for (int idx = threadIdx.x; idx < DM; idx += 256) {
        int t = idx >> 6, c = idx & 63;
        hm[(size_t)row*DM + idx] = h[((size_t)(b*20 + t)*30 + v)*64 + c];
    }
}
__global__ void hm2ht_k(const float* __restrict__ hm, float* __restrict__ ht){
    int row = blockIdx.x;          // b*20+t
    int b = row / 20, t = row % 20;
    for (int idx = threadIdx.x; idx < DTR_; idx += 256) {
        int v = idx >> 6, c = idx & 63;
        ht[(size_t)row*DTR_ + idx] = hm[((size_t)(b*30 + v))*DM + t*64 + c];
    }
}

// rmsnorm; o32/obf nullable
__global__ void rms_k(const float* __restrict__ x, const float* __restrict__ w,
                      const float* __restrict__ addv, int addDiv,
                      float* __restrict__ o32, u16* __restrict__ obf, int D){
    int row = blockIdx.x;
    const float* xr = x + (size_t)row*D;
    float ss = 0.f;
    for (int i = threadIdx.x; i < D; i += 256){ float v = xr[i]; ss += v*v; }
    ss = blockReduceSum(ss);
    float rs = rsqrtf(ss/(float)D + 1e-5f);
    const float* ap = addv ? addv + (size_t)(row/addDiv)*D : nullptr;
    for (int i = threadIdx.x; i < D; i += 256){
        float v = xr[i]*rs*w[i];
        if (ap) v += ap[i];
        if (o32) o32[(size_t)row*D + i] = v;
        if (obf) obf[(size_t)row*D + i] = bfbits(v);
    }
}

// layernorm -> bf16
__global__ void ln_bf_k(const float* __restrict__ x, const float* __restrict__ w,
                        const float* __restrict__ b, u16* __restrict__ obf, int D){
    int row = blockIdx.x;
    const float* xr = x + (size_t)row*D;
    float s1 = 0.f, s2 = 0.f;
    for (int i = threadIdx.x; i < D; i += 256){ float v = xr[i]; s1 += v; s2 += v*v; }
    s1 = blockReduceSum(s1);
    s2 = blockReduceSum(s2);
    float m = s1/(float)D, var = s2/(float)D - m*m, rs = rsqrtf(var + 1e-5f);
    for (int i = threadIdx.x; i < D; i += 256)
        obf[(size_t)row*D + i] = bfbits((xr[i] - m)*rs*w[i] + b[i]);
}

__global__ void convsilu_k(const float* __restrict__ xz, const float* __restrict__ cw,
                           const float* __restrict__ cb,
                           float* __restrict__ xc, u16* __restrict__ xcbf){
    int idx = blockIdx.x*256 + threadIdx.x;
    if (idx >= NB*NV*DI) return;
    int d = idx % DI; int bl = idx / DI; int l = bl % NV; int b = bl / NV;
    float acc = cb[d];
    #pragma unroll
    for (int k = 0; k < 4; ++k) {
        int ls = l - 3 + k;
        if (ls >= 0) acc += xz[((size_t)(b*NV + ls))*(2*DI) + d] * cw[d*4 + k];
    }
    float v = siluf(acc);
    xc[idx] = v;
    xcbf[idx] = bfbits(v);
}

// dbc fp32 [960,112] -> bf16 [960,128] zero-padded
__global__ void dbcconv_k(const float* __restrict__ dbc, u16* __restrict__ dbf){
    int i = blockIdx.x*256 + threadIdx.x;
    if (i >= NB*NV*128) return;
    int r = i >> 7, c = i & 127;
    dbf[i] = bfbits(c < 112 ? dbc[(size_t)r*112 + c] : 0.f);
}

__global__ __launch_bounds__(256) void scan_k(
    const float* __restrict__ delta, const float* __restrict__ dbc,
    const float* __restrict__ xc, const float* __restrict__ xz,
    const float* __restrict__ A_log, const float* __restrict__ Dp,
    u16* __restrict__ y2bf)
{
    __shared__ float sBC[30][32];
    int b = blockIdx.x / 10;
    int dblk = blockIdx.x % 10;
    int tid = threadIdx.x;
    for (int i = tid; i < 30*32; i += 256) {
        int l = i >> 5, j = i & 31;
        sBC[l][j] = dbc[((size_t)(b*NV + l))*112 + 80 + j];
    }
    __syncthreads();
    int d = dblk*256 + tid;
    float aA[16], s[16];
    #pragma unroll
    for (int n = 0; n < 16; ++n){ aA[n] = -expf(A_log[(size_t)d*16 + n]); s[n] = 0.f; }
    float dpv = Dp[d];
    for (int l = 0; l < NV; ++l) {
        size_t base = (size_t)(b*NV + l);
        float dv   = delta[base*DI + d];
        float xcv  = xc[base*DI + d];
        float resv = xz[base*(2*DI) + DI + d];
        float y = 0.f;
        #pragma unroll
        for (int n = 0; n < 16; ++n) {
            float dA = expf(dv*aA[n]);
            s[n] = dA*s[n] + dv*sBC[l][n]*xcv;
            y = fmaf(s[n], sBC[l][16 + n], y);
        }
        y2bf[base*DI + d] = bfbits((y + xcv*dpv) * siluf(resv));
    }
}

__global__ __launch_bounds__(64) void attn_k(const float* __restrict__ q,
                                             const float* __restrict__ k,
                                             const float* __restrict__ v,
                                             float* __restrict__ o){
    int idx = blockIdx.x;          // b*160 + t*8 + h
    int h = idx % 8; int bt = idx / 8; int t = bt % 20; int b = bt / 20;
    int lane = threadIdx.x;
    const float* qp = q + ((size_t)(b*20 + t))*DTR_ + h*DH;
    float qr[4];
    #pragma unroll
    for (int i = 0; i < 4; ++i){ int j = lane + i*64; qr[i] = (j < DH) ? qp[j] : 0.f; }
    __shared__ float sc[20];
    const float scale = 0.06454972243679028f;
    for (int s2 = 0; s2 < 20; ++s2) {
        const float* kp = k + ((size_t)(b*20 + s2))*DTR_ + h*DH;
        float p = 0.f;
        #pragma unroll
        for (int i = 0; i < 4; ++i){ int j = lane + i*64; if (j < DH) p = fmaf(qr[i], kp[j], p); }
        #pragma unroll
        for (int off = 32; off > 0; off >>= 1) p += __shfl_down(p, off, 64);
        if (lane == 0) sc[s2] = p*scale;
    }
    __syncthreads();
    float m = -1e30f;
    #pragma unroll
    for (int s2 = 0; s2 < 20; ++s2) m = fmaxf(m, sc[s2]);
    float ps[20]; float sum = 0.f;
    #pragma unroll
    for (int s2 = 0; s2 < 20; ++s2){ ps[s2] = expf(sc[s2] - m); sum += ps[s2]; }
    float inv = 1.f/sum;
    float acc[4] = {0.f,0.f,0.f,0.f};
    for (int s2 = 0; s2 < 20; ++s2) {
        const float* vp = v + ((size_t)(b*20 + s2))*DTR_ + h*DH;
        float w2 = ps[s2]*inv;
        #pragma unroll
        for (int i = 0; i < 4; ++i){ int j = lane + i*64; if (j < DH) acc[i] = fmaf(w2, vp[j], acc[i]); }
    }
    float* op = o + ((size_t)(b*20 + t))*DTR_ + h*DH;
    #pragma unroll
    for (int i = 0; i < 4; ++i){ int j = lane + i*64; if (j < DH) op[j] = acc[i]; }
}

__global__ void sty_ln_k(const float* __restrict__ x, const float* __restrict__ lw,
                         const float* __restrict__ lb, const float* __restrict__ ss,
                         u16* __restrict__ obf){
    int row = blockIdx.x;          // b*20+t
    int b = row / 20;
    const float* xr = x + (size_t)row*DTR_;
    float s1 = 0.f, s2 = 0.f;
    for (int i = threadIdx.x; i < DTR_; i += 256){ float v = xr[i]; s1 += v; s2 += v*v; }
    s1 = blockReduceSum(s1);
    s2 = blockReduceSum(s2);
    float m = s1/(float)DTR_, var = s2/(float)DTR_ - m*m, rs = rsqrtf(var + 1e-5f);
    const float* sb = ss + (size_t)b*(2*DTR_);
    for (int i = threadIdx.x; i < DTR_; i += 256) {
        float v = (xr[i] - m)*rs*lw[i] + lb[i];
        v = v*(1.f + sb[i]) + sb[DTR_ + i];
        obf[(size_t)row*DTR_ + i] = bfbits(siluf(v));
    }
}

__global__ void head_k(const float* __restrict__ fr, const float* __restrict__ W,
                       const float* __restrict__ bias, float* __restrict__ out){
    int row = blockIdx.x;          // b*20+t
    int tid = threadIdx.x;         // 48
    int v = tid/3, j = tid%3;
    const float* g = fr + (size_t)row*DTR_ + d_REV[v]*64;
    float acc = bias[j];
    #pragma unroll
    for (int c = 0; c < 64; ++c) acc = fmaf(g[c], W[c*3 + j], acc);
    out[(size_t)row*48 + tid] = acc;
}

// ---------------- host-side GEMM launcher ----------------
template<int BM, int ACT, int MODE>
static void G(hipStream_t st, const u16* A, int lda, const u16* B, int ldb,
              const float* bias, float* C, int ldc, u16* Cbf, int ldcb,
              int M, int N, int KT, int splitZ = 1)
{
    dim3 g((N + 127)/128, M/BM, splitZ), b(256);
    gemm_g_bk<BM,ACT,MODE><<<g, b, 0, st>>>(A,lda,B,ldb,bias,C,ldc,Cbf,ldcb,M,N,KT);
}

// ---------------- orchestration ----------------
extern "C" void kernel_launch(void* const* d_in, const int* in_sizes, int n_in,
                              void* d_out, int out_size, void* d_ws, size_t ws_size,
                              hipStream_t stream)
{
    const float* x        = (const float*)d_in[0];
    const int*   tst      = (const int*)  d_in[1];
    const float* seq_emb  = (const float*)d_in[2];
    const float* emb_W    = (const float*)d_in[3];
    const float* emb_b    = (const float*)d_in[4];
    const float* time_W1  = (const float*)d_in[5];
    const float* time_b1  = (const float*)d_in[6];
    const float* time_W2  = (const float*)d_in[7];
    const float* time_b2  = (const float*)d_in[8];
    const float* m_norm_w = (const float*)d_in[9];
    const float* m_emb_W  = (const float*)d_in[10];
    const float* m_emb_b  = (const float*)d_in[11];
    const float* m_in_W   = (const float*)d_in[12];
    const float* m_conv_w = (const float*)d_in[13];
    const float* m_conv_b = (const float*)d_in[14];
    const float* m_xproj_W= (const float*)d_in[15];
    const float* m_dt_W   = (const float*)d_in[16];
    const float* m_dt_b   = (const float*)d_in[17];
    const float* m_A_log  = (const float*)d_in[18];
    const float* m_D      = (const float*)d_in[19];
    const float* m_out_W  = (const float*)d_in[20];
    const float* t_ln1_w  = (const float*)d_in[21];
    const float* t_ln1_b  = (const float*)d_in[22];
    const float* t_Wq     = (const float*)d_in[23];
    const float* t_bq     = (const float*)d_in[24];
    const float* t_Wk     = (const float*)d_in[25];
    const float* t_bk     = (const float*)d_in[26];
    const float* t_Wv     = (const float*)d_in[27];
    const float* t_bv     = (const float*)d_in[28];
    const float* t_s1_eW  = (const float*)d_in[29];
    const float* t_s1_eb  = (const float*)d_in[30];
    const float* t_s1_lw  = (const float*)d_in[31];
    const float* t_s1_lb  = (const float*)d_in[32];
    const float* t_s1_oW  = (const float*)d_in[33];
    const float* t_s1_ob  = (const float*)d_in[34];
    const float* t_ln2_w  = (const float*)d_in[35];
    const float* t_ln2_b  = (const float*)d_in[36];
    const float* t_fW1    = (const float*)d_in[37];
    const float* t_fb1    = (const float*)d_in[38];
    const float* t_fW2    = (const float*)d_in[39];
    const float* t_fb2    = (const float*)d_in[40];
    const float* t_s2_eW  = (const float*)d_in[41];
    const float* t_s2_eb  = (const float*)d_in[42];
    const float* t_s2_lw  = (const float*)d_in[43];
    const float* t_s2_lb  = (const float*)d_in[44];
    const float* t_s2_oW  = (const float*)d_in[45];
    const float* t_s2_ob  = (const float*)d_in[46];
    const float* normf_w  = (const float*)d_in[47];
    const float* head_W   = (const float*)d_in[48];
    const float* head_b   = (const float*)d_in[49];

    float* ws = (float*)d_ws;
    size_t off = 0;
    auto allocf = [&](size_t n){ float* p = ws + off; off += (n + 3) & ~(size_t)3; return p; };
    auto allocu = [&](size_t n){ return (u16*)allocf((n + 1) / 2); };

    const size_t HSZ = (size_t)NB*NT*NV*JLD;      // 1,228,800
    // fp32
    float* emb   = allocf((size_t)NB*TEMPD);
    float* memb4 = allocf((size_t)4*NB*DM);
    float* ssb8  = allocf((size_t)8*NB*2*DTR_);
    float* h     = allocf(HSZ);
    float* pre0  = allocf(HSZ);
    float* pre1  = allocf(HSZ);
    float* hm    = allocf(HSZ);
    float* qb    = allocf(HSZ);
    float* kb    = allocf(HSZ);
    float* vb    = allocf(HSZ);
    float* aty   = allocf(HSZ);
    float* fr    = allocf(HSZ);
    float* xz    = allocf((size_t)NB*NV*2*DI);
    float* xcb   = allocf((size_t)NB*NV*DI);
    float* dbc   = allocf((size_t)NB*NV*112);
    float* delta = allocf((size_t)NB*NV*DI);
    // bf16 activations
    u16* embt_bf = allocu((size_t)NB*DM);
    u16* emb1_bf = allocu((size_t)NB*TEMPD);
    u16* emb_bf  = allocu((size_t)NB*TEMPD);
    u16* semb_bf = allocu((size_t)NB*TEMPD);
    u16* hn_bf   = allocu((size_t)NB*NV*DM);
    u16* xcb_bf  = allocu((size_t)NB*NV*DI);
    u16* dbc_bf  = allocu((size_t)NB*NV*128);
    u16* y2_bf   = allocu((size_t)NB*NV*DI);
    u16* xn_bf   = allocu((size_t)NB*NT*DTR_);
    u16* sty_bf  = allocu((size_t)NB*NT*DTR_);
    u16* mid_bf  = allocu((size_t)NB*NT*DI);
    // bf16 weights (upfront)
    u16* tw1   = allocu((size_t)TEMPD*DM);          // [512][1280]
    u16* tw2   = allocu((size_t)TEMPD*TEMPD);       // [512][512]
    u16* membW = allocu((size_t)4*DM*TEMPD);        // 4 x [1280][512]
    u16* ssbW  = allocu((size_t)8*2*DTR_*TEMPD);    // 8 x [3840][512]
    // bf16 weight slab (per-layer, reused)
    u16* s_in  = allocu((size_t)2*DI*DM);           // [5120][1280]
    u16* s_xp  = allocu((size_t)128*DI);            // [128][2560]
    u16* s_dt  = allocu((size_t)DI*128);            // [2560][128]
    u16* s_out = allocu((size_t)DM*DI);             // [1280][2560]
    u16* s_qkv = allocu((size_t)3*DTR_*DTR_);       // 3 x [1920][1920]
    u16* s_s1o = allocu((size_t)DTR_*DTR_);
    u16* s_s2o = allocu((size_t)DTR_*DTR_);
    u16* s_f1  = allocu((size_t)DI*DTR_);           // [2560][1920]
    u16* s_f2  = allocu((size_t)DTR_*DI);           // [1920][2560]
    (void)ws_size; (void)in_sizes; (void)n_in; (void)out_size;

    auto tiles = [](int Kp, int Np){ return (Np/64)*(Kp/64); };

    // ---- upfront weight conversion (1 launch) ----
    {
        ConvTab tb; int n = 0, tot = 0;
        auto add = [&](const float* src, u16* dst, int K, int N, int Kp, int Np){
            tb.e[n] = {src, dst, K, N, Kp, Np, tot}; tot += tiles(Kp, Np); ++n;
        };
        add(time_W1, tw1, DM, TEMPD, DM, TEMPD);
        add(time_W2, tw2, TEMPD, TEMPD, TEMPD, TEMPD);
        for (int l = 0; l < 4; ++l)
            add(m_emb_W + (size_t)l*TEMPD*DM, membW + (size_t)l*DM*TEMPD, TEMPD, DM, TEMPD, DM);
        for (int l = 0; l < 4; ++l)
            add(t_s1_eW + (size_t)l*TEMPD*2*DTR_, ssbW + (size_t)l*2*DTR_*TEMPD, TEMPD, 2*DTR_, TEMPD, 2*DTR_);
        for (int l = 0; l < 4; ++l)
            add(t_s2_eW + (size_t)l*TEMPD*2*DTR_, ssbW + (size_t)(4+l)*2*DTR_*TEMPD, TEMPD, 2*DTR_, TEMPD, 2*DTR_);
        tb.n = n;
        wconv_k<<<tot, 256, 0, stream>>>(tb);
    }

    // ---- time embedding + MLP ----
    tsemb_k<<<NB, 640, 0, stream>>>(tst, embt_bf);
    G<32,ACT_SILU,4>(stream, embt_bf, DM, tw1, DM, time_b1, nullptr, 0, emb1_bf, TEMPD, NB, TEMPD, 20);
    G<32,ACT_NONE,3>(stream, emb1_bf, TEMPD, tw2, TEMPD, time_b2, emb, TEMPD, emb_bf, TEMPD, NB, TEMPD, 8);
    silu_bf_v<<<(NB*TEMPD + 255)/256, 256, 0, stream>>>(emb, semb_bf, NB*TEMPD);

    // ---- hoisted per-layer emb projections ----
    {
        dim3 g1(DM/128, 1, 4), b(256);
        gemm_memb_bk<<<g1, b, 0, stream>>>(emb_bf, membW, m_emb_b, memb4);
        dim3 g2((2*DTR_)/128, 1, 8);
        gemm_ssb_bk<<<g2, b, 0, stream>>>(semb_bf, ssbW, t_s1_eb, t_s2_eb, ssb8);
    }

    // ---- vertex embedding + VORDER gather ----
    embed_k<<<NB*NT*NV, 64, 0, stream>>>(x, seq_emb, emb_W, emb_b, h);

    for (int i = 0; i < 4; ++i) {
        // per-layer weight conversion into slab (1 launch)
        {
            ConvTab tb; int n = 0, tot = 0;
            auto add = [&](const float* src, u16* dst, int K, int N, int Kp, int Np){
                tb.e[n] = {src, dst, K, N, Kp, Np, tot}; tot += tiles(Kp, Np); ++n;
            };
            add(m_in_W   + (size_t)i*DM*2*DI,     s_in,  DM, 2*DI, DM, 2*DI);
            add(m_xproj_W+ (size_t)i*DI*112,      s_xp,  DI, 112, DI, 128);
            add(m_dt_W   + (size_t)i*DTRANK*DI,   s_dt,  DTRANK, DI, 128, DI);
            add(m_out_W  + (size_t)i*DI*DM,       s_out, DI, DM, DI, DM);
            add(t_Wq     + (size_t)i*DTR_*DTR_,   s_qkv,                      DTR_, DTR_, DTR_, DTR_);
            add(t_Wk     + (size_t)i*DTR_*DTR_,   s_qkv + (size_t)DTR_*DTR_,  DTR_, DTR_, DTR_, DTR_);
            add(t_Wv     + (size_t)i*DTR_*DTR_,   s_qkv + (size_t)2*DTR_*DTR_,DTR_, DTR_, DTR_, DTR_);
            add(t_s1_oW  + (size_t)i*DTR_*DTR_,   s_s1o, DTR_, DTR_, DTR_, DTR_);
            add(t_s2_oW  + (size_t)i*DTR_*DTR_,   s_s2o, DTR_, DTR_, DTR_, DTR_);
            add(t_fW1    + (size_t)i*DTR_*DI,     s_f1,  DTR_, DI, DTR_, DI);
            add(t_fW2    + (size_t)i*DI*DTR_,     s_f2,  DI, DTR_, DI, DTR_);
            tb.n = n;
            wconv_k<<<tot, 256, 0, stream>>>(tb);
        }

        if (i == 0) copy_v<<<(int)((HSZ + 255)/256), 256, 0, stream>>>(h, pre0, (int)HSZ);
        if (i == 1) copy_v<<<(int)((HSZ + 255)/256), 256, 0, stream>>>(h, pre1, (int)HSZ);

        // ---- mamba half ----
        h2hm_k<<<NB*NV, 256, 0, stream>>>(h, hm);
        rms_k<<<NB*NV, 256, 0, stream>>>(hm, m_norm_w + (size_t)i*DM,
                                         memb4 + (size_t)i*NB*DM, NV, nullptr, hn_bf, DM);
        G<64,ACT_NONE,0>(stream, hn_bf, DM, s_in, DM, nullptr, xz, 2*DI, nullptr, 0, NB*NV, 2*DI, 20);
        convsilu_k<<<(NB*NV*DI + 255)/256, 256, 0, stream>>>(
            xz, m_conv_w + (size_t)i*DI*4, m_conv_b + (size_t)i*DI, xcb, xcb_bf);
        zero_k<<<(NB*NV*112 + 255)/256, 256, 0, stream>>>(dbc, NB*NV*112);
        G<32,ACT_NONE,2>(stream, xcb_bf, DI, s_xp, DI, nullptr, dbc, 112, nullptr, 0, NB*NV, 112, 5, 8);
        dbcconv_k<<<(NB*NV*128 + 255)/256, 256, 0, stream>>>(dbc, dbc_bf);
        G<64,ACT_SOFTPLUS,0>(stream, dbc_bf, 128, s_dt, 128, m_dt_b + (size_t)i*DI,
                             delta, DI, nullptr, 0, NB*NV, DI, 2);
        scan_k<<<NB*10, 256, 0, stream>>>(delta, dbc, xcb, xz,
             m_A_log + (size_t)i*DI*DSTATE, m_D + (size_t)i*DI, y2_bf);
        G<32,ACT_NONE,1>(stream, y2_bf, DI, s_out, DI, nullptr, hm, DM, nullptr, 0, NB*NV, DM, 40);
        hm2ht_k<<<NB*NT, 256, 0, stream>>>(hm, h);

        // ---- transformer half ----
        ln_bf_k<<<NB*NT, 256, 0, stream>>>(h, t_ln1_w + (size_t)i*DTR_, t_ln1_b + (size_t)i*DTR_, xn_bf, DTR_);
        {
            dim3 g(DTR_/128, (NB*NT)/32, 3), b(256);
            gemm_qkv_bk<<<g, b, 0, stream>>>(xn_bf, s_qkv,
                t_bq + (size_t)i*DTR_, t_bk + (size_t)i*DTR_, t_bv + (size_t)i*DTR_,
                qb, kb, vb);
        }
        attn_k<<<NB*NT*NHEAD_, 64, 0, stream>>>(qb, kb, vb, aty);

        sty_ln_k<<<NB*NT, 256, 0, stream>>>(aty, t_s1_lw + (size_t)i*DTR_, t_s1_lb + (size_t)i*DTR_,
                                            ssb8 + (size_t)i*NB*2*DTR_, sty_bf);
        G<32,ACT_NONE,1>(stream, sty_bf, DTR_, s_s1o, DTR_, t_s1_ob + (size_t)i*DTR_,
                         h, DTR_, nullptr, 0, NB*NT, DTR_, 30);

        ln_bf_k<<<NB*NT, 256, 0, stream>>>(h, t_ln2_w + (size_t)i*DTR_, t_ln2_b + (size_t)i*DTR_, xn_bf, DTR_);
        G<32,ACT_GELU,4>(stream, xn_bf, DTR_, s_f1, DTR_, t_fb1 + (size_t)i*DI,
                         nullptr, 0, mid_bf, DI, NB*NT, DI, 30);
        G<32,ACT_NONE,0>(stream, mid_bf, DI, s_f2, DI, t_fb2 + (size_t)i*DTR_,
                         aty, DTR_, nullptr, 0, NB*NT, DTR_, 40);

        sty_ln_k<<<NB*NT, 256, 0, stream>>>(aty, t_s2_lw + (size_t)i*DTR_, t_s2_lb + (size_t)i*DTR_,
                                            ssb8 + (size_t)(4 + i)*NB*2*DTR_, sty_bf);
        G<32,ACT_NONE,1>(stream, sty_bf, DTR_, s_s2o, DTR_, t_s2_ob + (size_t)i*DTR_,
                         h, DTR_, nullptr, 0, NB*NT, DTR_, 30);

        if (i == 2) add_v<<<(int)((HSZ + 255)/256), 256, 0, stream>>>(pre1, h, (int)HSZ);
        if (i == 3) add_v<<<(int)((HSZ + 255)/256), 256, 0, stream>>>(pre0, h, (int)HSZ);
    }

    // final rmsnorm + REV gather + head
    rms_k<<<NB*NT, 256, 0, stream>>>(h, normf_w, nullptr, 1, fr, nullptr, DTR_);
    head_k<<<NB*NT, 48, 0, stream>>>(fr, head_W, head_b, (float*)d_out);
}

// Round 7
// 1884.744 us; speedup vs baseline: 4.2928x; 1.0042x over previous
//
#include <hip/hip_runtime.h>
#include <hip/hip_bf16.h>
#include <math.h>

// ---------------- constants ----------------
#define NB 32
#define NT 20
#define NV 30
#define JLD 64
#define DM 1280
#define DTR_ 1920
#define DI 2560
#define DSTATE 16
#define DTRANK 80
#define TEMPD 512
#define NHEAD_ 8
#define DH 240

__constant__ int d_VORDER[30] = {9,8,7,10,11,12,11,10,7,13,14,15,14,13,7,6,0,1,2,1,0,6,3,4,5,4,3,6,7,8};
__constant__ int d_REV[16]    = {20,19,18,26,25,24,27,28,29,0,7,6,5,13,12,11};

typedef unsigned short u16;
typedef __bf16 bf16x8 __attribute__((ext_vector_type(8)));
typedef float f32x4  __attribute__((ext_vector_type(4)));

__device__ __forceinline__ float siluf(float x){ return x / (1.f + expf(-x)); }
__device__ __forceinline__ float geluf(float x){
    float x3 = x*x*x;
    return 0.5f*x*(1.f + tanhf(0.7978845608028654f*(x + 0.044715f*x3)));
}
__device__ __forceinline__ float softplusf(float x){
    return fmaxf(x, 0.f) + log1pf(expf(-fabsf(x)));
}
__device__ __forceinline__ u16 bfbits(float x){
    return __builtin_bit_cast(u16, (__bf16)x);
}

__device__ __forceinline__ void gload16(const void* g, void* l){
    __builtin_amdgcn_global_load_lds(
        (const __attribute__((address_space(1))) void*)g,
        (__attribute__((address_space(3))) void*)l, 16, 0, 0);
}

__device__ __forceinline__ float blockReduceSum(float v){
    #pragma unroll
    for (int off = 32; off > 0; off >>= 1) v += __shfl_down(v, off, 64);
    __shared__ float sred[4];
    __shared__ float stot;
    int w = threadIdx.x >> 6;
    if ((threadIdx.x & 63) == 0) sred[w] = v;
    __syncthreads();
    if (threadIdx.x == 0) stot = sred[0] + sred[1] + sred[2] + sred[3];
    __syncthreads();
    return stot;
}

enum { ACT_NONE=0, ACT_SILU=1, ACT_GELU=2, ACT_SOFTPLUS=3 };
// MODE: 0 store f32 | 1 += f32 | 2 atomicAdd f32 | 3 store f32+bf16 | 4 store bf16
//       5 C += v + aux (fused skip-add) | 6 C += v, also write result to aux

// ---------------- bf16 MFMA GEMM, global_load_lds + counted vmcnt ----------------
template<int BM, int ACT, int MODE>
__device__ __forceinline__ void gemm_dev(
    const u16* __restrict__ A, int lda,
    const u16* __restrict__ B, int ldb,
    const float* __restrict__ bias,
    float* __restrict__ C, int ldc,
    u16* __restrict__ Cbf, int ldcb,
    float* __restrict__ aux,
    int M, int N, int KT, int bm, int bn, int ktb)
{
    constexpr int HALF = (BM + 128) * 128;
    constexpr int L    = (BM + 128) * 8 / 256;
    constexpr int MI   = BM / 32;

    __shared__ char lds[2 * HALF];

    const int tid = threadIdx.x, lane = tid & 63, wv = tid >> 6;
    const int wm = (wv >> 1) * (BM / 2), wn = (wv & 1) * 64;

    f32x4 acc[MI][4];
    #pragma unroll
    for (int i = 0; i < MI; ++i)
        #pragma unroll
        for (int j = 0; j < 4; ++j) acc[i][j] = (f32x4){0.f,0.f,0.f,0.f};

    auto stage = [&](int buf, int kt){
        const int kofs = kt * 64;
        #pragma unroll
        for (int i = 0; i < L; ++i) {
            int gb = i*256 + wv*64;
            int g  = gb + lane;
            const u16* src;
            if (i*256 < BM*8) {
                int row = g >> 3, slot = g & 7;
                src = A + (size_t)(bm + row)*lda + kofs + ((slot ^ (row & 7)) << 3);
            } else {
                int g2 = g - BM*8;
                int row = g2 >> 3, slot = g2 & 7;
                src = B + (size_t)(bn + row)*ldb + kofs + ((slot ^ (row & 7)) << 3);
            }
            gload16(src, lds + buf*HALF + gb*16);
        }
    };
    auto compute = [&](int buf){
        const char* Ab = lds + buf*HALF;
        const char* Bb = Ab + BM*128;
        #pragma unroll
        for (int kk = 0; kk < 2; ++kk) {
            int ks = kk*4 + (lane >> 4);
            bf16x8 af[MI], bfr[4];
            #pragma unroll
            for (int mi = 0; mi < MI; ++mi) {
                int row = wm + mi*16 + (lane & 15);
                af[mi] = *(const bf16x8*)(Ab + row*128 + ((ks ^ (row & 7)) << 4));
            }
            #pragma unroll
            for (int ni = 0; ni < 4; ++ni) {
                int n = wn + ni*16 + (lane & 15);
                bfr[ni] = *(const bf16x8*)(Bb + n*128 + ((ks ^ (n & 7)) << 4));
            }
            #pragma unroll
            for (int mi = 0; mi < MI; ++mi)
                #pragma unroll
                for (int ni = 0; ni < 4; ++ni)
                    acc[mi][ni] = __builtin_amdgcn_mfma_f32_16x16x32_bf16(
                        af[mi], bfr[ni], acc[mi][ni], 0, 0, 0);
        }
    };

    stage(0, ktb);
    int cur = 0;
    for (int t = 0; t < KT; ++t) {
        if (t + 1 < KT) {
            stage(cur ^ 1, ktb + t + 1);
            if constexpr (BM == 32) asm volatile("s_waitcnt vmcnt(5)" ::: "memory");
            else                    asm volatile("s_waitcnt vmcnt(6)" ::: "memory");
        } else {
            asm volatile("s_waitcnt vmcnt(0)" ::: "memory");
        }
        __builtin_amdgcn_sched_barrier(0);
        __builtin_amdgcn_s_barrier();
        __builtin_amdgcn_sched_barrier(0);
        compute(cur);
        __builtin_amdgcn_sched_barrier(0);
        __builtin_amdgcn_s_barrier();
        __builtin_amdgcn_sched_barrier(0);
        cur ^= 1;
    }

    const int rb = (lane >> 4) * 4, cb = lane & 15;
    #pragma unroll
    for (int mi = 0; mi < MI; ++mi) {
        #pragma unroll
        for (int r = 0; r < 4; ++r) {
            int row = bm + wm + mi*16 + rb + r;
            #pragma unroll
            for (int ni = 0; ni < 4; ++ni) {
                int col = bn + wn + ni*16 + cb;
                if (col >= N) continue;
                float v = acc[mi][ni][r];
                if (bias) v += bias[col];
                if (ACT == ACT_SILU)     v = siluf(v);
                if (ACT == ACT_GELU)     v = geluf(v);
                if (ACT == ACT_SOFTPLUS) v = softplusf(v);
                size_t idx = (size_t)row*ldc + col;
                if (MODE == 1)      C[idx] += v;
                else if (MODE == 2) atomicAdd(&C[idx], v);
                else if (MODE == 5) C[idx] = C[idx] + v + aux[idx];
                else if (MODE == 6) { float t2 = C[idx] + v; C[idx] = t2; aux[idx] = t2; }
                else {
                    if (MODE != 4) C[idx] = v;
                    if (MODE >= 3) Cbf[(size_t)row*ldcb + col] = bfbits(v);
                }
            }
        }
    }
    (void)M;
}

template<int BM, int ACT, int MODE>
__global__ __launch_bounds__(256) void gemm_g_bk(
    const u16* __restrict__ A, int lda, const u16* __restrict__ B, int ldb,
    const float* __restrict__ bias, float* __restrict__ C, int ldc,
    u16* __restrict__ Cbf, int ldcb, float* __restrict__ aux,
    int M, int N, int KT)
{
    gemm_dev<BM,ACT,MODE>(A,lda,B,ldb,bias,C,ldc,Cbf,ldcb,aux,M,N,KT,
                          blockIdx.y*BM, blockIdx.x*128, blockIdx.z*KT);
}

__global__ __launch_bounds__(256) void gemm_qkv_bk(
    const u16* __restrict__ A, const u16* __restrict__ Wqkv,
    const float* __restrict__ bq, const float* __restrict__ bk2, const float* __restrict__ bv,
    float* __restrict__ oq, float* __restrict__ ok2, float* __restrict__ ov)
{
    int z = blockIdx.z;
    const float* bb = (z == 0) ? bq : (z == 1) ? bk2 : bv;
    float*       cc = (z == 0) ? oq : (z == 1) ? ok2 : ov;
    gemm_dev<32,ACT_NONE,0>(A, DTR_, Wqkv + (size_t)z*DTR_*DTR_, DTR_, bb,
                            cc, DTR_, nullptr, 0, nullptr, NB*NT, DTR_, 30,
                            blockIdx.y*32, blockIdx.x*128, 0);
}

__global__ __launch_bounds__(256) void gemm_memb_bk(
    const u16* __restrict__ A, const u16* __restrict__ W,
    const float* __restrict__ bias, float* __restrict__ Cc)
{
    int z = blockIdx.z;
    gemm_dev<32,ACT_NONE,0>(A, TEMPD, W + (size_t)z*DM*TEMPD, TEMPD, bias + (size_t)z*DM,
                            Cc + (size_t)z*NB*DM, DM, nullptr, 0, nullptr, NB, DM, 8,
                            blockIdx.y*32, blockIdx.x*128, 0);
}

__global__ __launch_bounds__(256) void gemm_ssb_bk(
    const u16* __restrict__ A, const u16* __restrict__ W,
    const float* __restrict__ b1, const float* __restrict__ b2, float* __restrict__ Cc)
{
    int z = blockIdx.z;
    const float* bb = (z < 4) ? b1 + (size_t)z*2*DTR_ : b2 + (size_t)(z-4)*2*DTR_;
    gemm_dev<32,ACT_NONE,0>(A, TEMPD, W + (size_t)z*2*DTR_*TEMPD, TEMPD, bb,
                            Cc + (size_t)z*NB*2*DTR_, 2*DTR_, nullptr, 0, nullptr, NB, 2*DTR_, 8,
                            blockIdx.y*32, blockIdx.x*128, 0);
}

// ---------------- weight transpose+convert: fp32[K,N] -> bf16[Np,Kp], zero-padded ----------------
struct ConvEnt { const float* src; u16* dst; int K, N, Kp, Np, tile0; };
struct ConvTab { ConvEnt e[64]; int n; };

__global__ __launch_bounds__(256) void wconv_k(ConvTab tab){
    int t = blockIdx.x;
    int i = 0;
    while (i + 1 < tab.n && tab.e[i+1].tile0 <= t) ++i;
    const float* src = tab.e[i].src;
    u16* dst = tab.e[i].dst;
    const int K = tab.e[i].K, N = tab.e[i].N, Kp = tab.e[i].Kp, Np = tab.e[i].Np;
    int lt = t - tab.e[i].tile0;
    int nx = Np >> 6;
    int n0 = (lt % nx) << 6, k0 = (lt / nx) << 6;

    __shared__ u16 tile[64][72];
    const int tid = threadIdx.x;
    {
        int r = tid >> 2, cs = (tid & 3) << 4;
        int gk = k0 + r;
        #pragma unroll
        for (int j = 0; j < 16; j += 4) {
            int gn = n0 + cs + j;
            float4 v = make_float4(0.f,0.f,0.f,0.f);
            if (gk < K) {
                if (gn + 3 < N) v = *(const float4*)(src + (size_t)gk*N + gn);
                else {
                    float tmp[4] = {0.f,0.f,0.f,0.f};
                    for (int e2 = 0; e2 < 4; ++e2) if (gn + e2 < N) tmp[e2] = src[(size_t)gk*N + gn + e2];
                    v = make_float4(tmp[0],tmp[1],tmp[2],tmp[3]);
                }
            }
            tile[r][cs+j+0] = bfbits(v.x);
            tile[r][cs+j+1] = bfbits(v.y);
            tile[r][cs+j+2] = bfbits(v.z);
            tile[r][cs+j+3] = bfbits(v.w);
        }
    }
    __syncthreads();
    {
        int n = tid >> 2, ks = (tid & 3) << 4;
        u16 outv[16];
        #pragma unroll
        for (int j = 0; j < 16; ++j) outv[j] = tile[ks + j][n];
        u16* dp = dst + (size_t)(n0 + n)*Kp + k0 + ks;
        *(uint4*)dp       = *(uint4*)&outv[0];
        *(uint4*)(dp + 8) = *(uint4*)&outv[8];
    }
}

// ---------------- small kernels ----------------

__global__ void tsemb_k(const int* __restrict__ t, u16* __restrict__ o){
    int b = blockIdx.x, j = threadIdx.x;   // 640
    float f = expf(-9.210340371976184f * (float)j / 640.f);
    float a = (float)t[b] * f;
    o[b*DM + j]       = bfbits(cosf(a));
    o[b*DM + 640 + j] = bfbits(sinf(a));
}

__global__ void silu_bf_v(const float* __restrict__ a, u16* __restrict__ o, int n){
    int i = blockIdx.x*256 + threadIdx.x; if (i < n) o[i] = bfbits(siluf(a[i]));
}
__global__ void zero_k(float* __restrict__ p, int n){
    int i = blockIdx.x*256 + threadIdx.x; if (i < n) p[i] = 0.f;
}

// embed + VORDER gather; writes h AND pre0 (skip for layer 3)
__global__ void embed_k(const float* __restrict__ x, const float* __restrict__ seq_emb,
                        const float* __restrict__ eW, const float* __restrict__ eb,
                        float* __restrict__ h, float* __restrict__ pre0){
    int i = blockIdx.x;            // b*600 + t*30 + vo
    int c = threadIdx.x;           // 64
    int vo = i % 30; int bt = i / 30; int t = bt % 20; int b = bt / 20;
    int v = d_VORDER[vo];
    const float* xp = x + (size_t)(b*20 + t)*48 + v*3;
    float val = eb[c] + seq_emb[(size_t)(t*16 + v)*64 + c]
              + xp[0]*eW[c] + xp[1]*eW[64 + c] + xp[2]*eW[128 + c];
    h[(size_t)i*64 + c] = val;
    pre0[(size_t)i*64 + c] = val;
}

// fused (b,t,v,c)->(b,v,t*64+c) transpose + rmsnorm(+memb add); writes hm (raw) and hn_bf
__global__ void rms_t_k(const float* __restrict__ h, const float* __restrict__ w,
                        const float* __restrict__ memb,
                        float* __restrict__ hm, u16* __restrict__ hn_bf){
    int row = blockIdx.x;          // b*30+v
    int b = row / 30, v = row % 30;
    float ss = 0.f;
    for (int idx = threadIdx.x; idx < DM; idx += 256) {
        int t = idx >> 6, c = idx & 63;
        float val = h[((size_t)(b*20 + t)*30 + v)*64 + c];
        hm[(size_t)row*DM + idx] = val;
        ss += val*val;
    }
    ss = blockReduceSum(ss);
    float rs = rsqrtf(ss/(float)DM + 1e-5f);
    const float* ap = memb + (size_t)b*DM;
    for (int idx = threadIdx.x; idx < DM; idx += 256) {
        float val = hm[(size_t)row*DM + idx];
        hn_bf[(size_t)row*DM + idx] = bfbits(val*rs*w[idx] + ap[idx]);
    }
}

// fused (b,v,t*64+c)->(b,t,v*64+c) transpose + layernorm; writes h (ht) and xn_bf
__global__ void hm2ht_ln_k(const float* __restrict__ hm, const float* __restrict__ w,
                           const float* __restrict__ bias,
                           float* __restrict__ h, u16* __restrict__ xn_bf){
    int row = blockIdx.x;          // b*20+t
    int b = row / 20, t = row % 20;
    float s1 = 0.f, s2 = 0.f;
    for (int idx = threadIdx.x; idx < DTR_; idx += 256) {
        int v = idx >> 6, c = idx & 63;
        float val = hm[((size_t)(b*30 + v))*DM + t*64 + c];
        h[(size_t)row*DTR_ + idx] = val;
        s1 += val; s2 += val*val;
    }
    s1 = blockReduceSum(s1);
    s2 = blockReduceSum(s2);
    float m = s1/(float)DTR_, var = s2/(float)DTR_ - m*m, rs = rsqrtf(var + 1e-5f);
    for (int idx = threadIdx.x; idx < DTR_; idx += 256) {
        float val = h[(size_t)row*DTR_ + idx];
        xn_bf[(size_t)row*DTR_ + idx] = bfbits((val - m)*rs*w[idx] + bias[idx]);
    }
}

// layernorm -> bf16 (standard layout input)
__global__ void ln_bf_k(const float* __restrict__ x, const float* __restrict__ w,
                        const float* __restrict__ b, u16* __restrict__ obf, int D){
    int row = blockIdx.x;
    const float* xr = x + (size_t)row*D;
    float s1 = 0.f, s2 = 0.f;
    for (int i = threadIdx.x; i < D; i += 256){ float v = xr[i]; s1 += v; s2 += v*v; }
    s1 = blockReduceSum(s1);
    s2 = blockReduceSum(s2);
    float m = s1/(float)D, var = s2/(float)D - m*m, rs = rsqrtf(var + 1e-5f);
    for (int i = threadIdx.x; i < D; i += 256)
        obf[(size_t)row*D + i] = bfbits((xr[i] - m)*rs*w[i] + b[i]);
}

__global__ void convsilu_k(const float* __restrict__ xz, const float* __restrict__ cw,
                           const float* __restrict__ cb,
                           float* __restrict__ xc, u16* __restrict__ xcbf){
    int idx = blockIdx.x*256 + threadIdx.x;
    if (idx >= NB*NV*DI) return;
    int d = idx % DI; int bl = idx / DI; int l = bl % NV; int b = bl / NV;
    float acc = cb[d];
    #pragma unroll
    for (int k = 0; k < 4; ++k) {
        int ls = l - 3 + k;
        if (ls >= 0) acc += xz[((size_t)(b*NV + ls))*(2*DI) + d] * cw[d*4 + k];
    }
    float v = siluf(acc);
    xc[idx] = v;
    xcbf[idx] = bfbits(v);
}

__global__ void dbcconv_k(const float* __restrict__ dbc, u16* __restrict__ dbf){
    int i = blockIdx.x*256 + threadIdx.x;
    if (i >= NB*NV*128) return;
    int r = i >> 7, c = i & 127;
    dbf[i] = bfbits(c < 112 ? dbc[(size_t)r*112 + c] : 0.f);
}

__global__ __launch_bounds__(256) void scan_k(
    const float* __restrict__ delta, const float* __restrict__ dbc,
    const float* __restrict__ xc, const float* __restrict__ xz,
    const float* __restrict__ A_log, const float* __restrict__ Dp,
    u16* __restrict__ y2bf)
{
    __shared__ float sBC[30][32];
    int b = blockIdx.x / 10;
    int dblk = blockIdx.x % 10;
    int tid = threadIdx.x;
    for (int i = tid; i < 30*32; i += 256) {
        int l = i >> 5, j = i & 31;
        sBC[l][j] = dbc[((size_t)(b*NV + l))*112 + 80 + j];
    }
    __syncthreads();
    int d = dblk*256 + tid;
    float aA[16], s[16];
    #pragma unroll
    for (int n = 0; n < 16; ++n){ aA[n] = -expf(A_log[(size_t)d*16 + n]); s[n] = 0.f; }
    float dpv = Dp[d];
    for (int l = 0; l < NV; ++l) {
        size_t base = (size_t)(b*NV + l);
        float dv   = delta[base*DI + d];
        float xcv  = xc[base*DI + d];
        float resv = xz[base*(2*DI) + DI + d];
        float y = 0.f;
        #pragma unroll
        for (int n = 0; n < 16; ++n) {
            float dA = expf(dv*aA[n]);
            s[n] = dA*s[n] + dv*sBC[l][n]*xcv;
            y = fmaf(s[n], sBC[l][16 + n], y);
        }
        y2bf[base*DI + d] = bfbits((y + xcv*dpv) * siluf(resv));
    }
}

__global__ __launch_bounds__(64) void attn_k(const float* __restrict__ q,
                                             const float* __restrict__ k,
                                             const float* __restrict__ v,
                                             float* __restrict__ o){
    int idx = blockIdx.x;          // b*160 + t*8 + h
    int h = idx % 8; int bt = idx / 8; int t = bt % 20; int b = bt / 20;
    int lane = threadIdx.x;
    const float* qp = q + ((size_t)(b*20 + t))*DTR_ + h*DH;
    float qr[4];
    #pragma unroll
    for (int i = 0; i < 4; ++i){ int j = lane + i*64; qr[i] = (j < DH) ? qp[j] : 0.f; }
    __shared__ float sc[20];
    const float scale = 0.06454972243679028f;
    for (int s2 = 0; s2 < 20; ++s2) {
        const float* kp = k + ((size_t)(b*20 + s2))*DTR_ + h*DH;
        float p = 0.f;
        #pragma unroll
        for (int i = 0; i < 4; ++i){ int j = lane + i*64; if (j < DH) p = fmaf(qr[i], kp[j], p); }
        #pragma unroll
        for (int off = 32; off > 0; off >>= 1) p += __shfl_down(p, off, 64);
        if (lane == 0) sc[s2] = p*scale;
    }
    __syncthreads();
    float m = -1e30f;
    #pragma unroll
    for (int s2 = 0; s2 < 20; ++s2) m = fmaxf(m, sc[s2]);
    float ps[20]; float sum = 0.f;
    #pragma unroll
    for (int s2 = 0; s2 < 20; ++s2){ ps[s2] = expf(sc[s2] - m); sum += ps[s2]; }
    float inv = 1.f/sum;
    float acc[4] = {0.f,0.f,0.f,0.f};
    for (int s2 = 0; s2 < 20; ++s2) {
        const float* vp = v + ((size_t)(b*20 + s2))*DTR_ + h*DH;
        float w2 = ps[s2]*inv;
        #pragma unroll
        for (int i = 0; i < 4; ++i){ int j = lane + i*64; if (j < DH) acc[i] = fmaf(w2, vp[j], acc[i]); }
    }
    float* op = o + ((size_t)(b*20 + t))*DTR_ + h*DH;
    #pragma unroll
    for (int i = 0; i < 4; ++i){ int j = lane + i*64; if (j < DH) op[j] = acc[i]; }
}

__global__ void sty_ln_k(const float* __restrict__ x, const float* __restrict__ lw,
                         const float* __restrict__ lb, const float* __restrict__ ss,
                         u16* __restrict__ obf){
    int row = blockIdx.x;          // b*20+t
    int b = row / 20;
    const float* xr = x + (size_t)row*DTR_;
    float s1 = 0.f, s2 = 0.f;
    for (int i = threadIdx.x; i < DTR_; i += 256){ float v = xr[i]; s1 += v; s2 += v*v; }
    s1 = blockReduceSum(s1);
    s2 = blockReduceSum(s2);
    float m = s1/(float)DTR_, var = s2/(float)DTR_ - m*m, rs = rsqrtf(var + 1e-5f);
    const float* sb = ss + (size_t)b*(2*DTR_);
    for (int i = threadIdx.x; i < DTR_; i += 256) {
        float v = (xr[i] - m)*rs*lw[i] + lb[i];
        v = v*(1.f + sb[i]) + sb[DTR_ + i];
        obf[(size_t)row*DTR_ + i] = bfbits(siluf(v));
    }
}

__global__ void rms_f_k(const float* __restrict__ x, const float* __restrict__ w,
                        float* __restrict__ o, int D){
    int row = blockIdx.x;
    const float* xr = x + (size_t)row*D;
    float ss = 0.f;
    for (int i = threadIdx.x; i < D; i += 256){ float v = xr[i]; ss += v*v; }
    ss = blockReduceSum(ss);
    float rs = rsqrtf(ss/(float)D + 1e-5f);
    for (int i = threadIdx.x; i < D; i += 256)
        o[(size_t)row*D + i] = xr[i]*rs*w[i];
}

__global__ void head_k(const float* __restrict__ fr, const float* __restrict__ W,
                       const float* __restrict__ bias, float* __restrict__ out){
    int row = blockIdx.x;          // b*20+t
    int tid = threadIdx.x;         // 48
    int v = tid/3, j = tid%3;
    const float* g = fr + (size_t)row*DTR_ + d_REV[v]*64;
    float acc = bias[j];
    #pragma unroll
    for (int c = 0; c < 64; ++c) acc = fmaf(g[c], W[c*3 + j], acc);
    out[(size_t)row*48 + tid] = acc;
}

// ---------------- host-side GEMM launcher ----------------
template<int BM, int ACT, int MODE>
static void G(hipStream_t st, const u16* A, int lda, const u16* B, int ldb,
              const float* bias, float* C, int ldc, u16* Cbf, int ldcb,
              int M, int N, int KT, int splitZ = 1, float* aux = nullptr)
{
    dim3 g((N + 127)/128, M/BM, splitZ), b(256);
    gemm_g_bk<BM,ACT,MODE><<<g, b, 0, st>>>(A,lda,B,ldb,bias,C,ldc,Cbf,ldcb,aux,M,N,KT);
}

// ---------------- orchestration ----------------
extern "C" void kernel_launch(void* const* d_in, const int* in_sizes, int n_in,
                              void* d_out, int out_size, void* d_ws, size_t ws_size,
                              hipStream_t stream)
{
    const float* x        = (const float*)d_in[0];
    const int*   tst      = (const int*)  d_in[1];
    const float* seq_emb  = (const float*)d_in[2];
    const float* emb_W    = (const float*)d_in[3];
    const float* emb_b    = (const float*)d_in[4];
    const float* time_W1  = (const float*)d_in[5];
    const float* time_b1  = (const float*)d_in[6];
    const float* time_W2  = (const float*)d_in[7];
    const float* time_b2  = (const float*)d_in[8];
    const float* m_norm_w = (const float*)d_in[9];
    const float* m_emb_W  = (const float*)d_in[10];
    const float* m_emb_b  = (const float*)d_in[11];
    const float* m_in_W   = (const float*)d_in[12];
    const float* m_conv_w = (const float*)d_in[13];
    const float* m_conv_b = (const float*)d_in[14];
    const float* m_xproj_W= (const float*)d_in[15];
    const float* m_dt_W   = (const float*)d_in[16];
    const float* m_dt_b   = (const float*)d_in[17];
    const float* m_A_log  = (const float*)d_in[18];
    const float* m_D      = (const float*)d_in[19];
    const float* m_out_W  = (const float*)d_in[20];
    const float* t_ln1_w  = (const float*)d_in[21];
    const float* t_ln1_b  = (const float*)d_in[22];
    const float* t_Wq     = (const float*)d_in[23];
    const float* t_bq     = (const float*)d_in[24];
    const float* t_Wk     = (const float*)d_in[25];
    const float* t_bk     = (const float*)d_in[26];
    const float* t_Wv     = (const float*)d_in[27];
    const float* t_bv     = (const float*)d_in[28];
    const float* t_s1_eW  = (const float*)d_in[29];
    const float* t_s1_eb  = (const float*)d_in[30];
    const float* t_s1_lw  = (const float*)d_in[31];
    const float* t_s1_lb  = (const float*)d_in[32];
    const float* t_s1_oW  = (const float*)d_in[33];
    const float* t_s1_ob  = (const float*)d_in[34];
    const float* t_ln2_w  = (const float*)d_in[35];
    const float* t_ln2_b  = (const float*)d_in[36];
    const float* t_fW1    = (const float*)d_in[37];
    const float* t_fb1    = (const float*)d_in[38];
    const float* t_fW2    = (const float*)d_in[39];
    const float* t_fb2    = (const float*)d_in[40];
    const float* t_s2_eW  = (const float*)d_in[41];
    const float* t_s2_eb  = (const float*)d_in[42];
    const float* t_s2_lw  = (const float*)d_in[43];
    const float* t_s2_lb  = (const float*)d_in[44];
    const float* t_s2_oW  = (const float*)d_in[45];
    const float* t_s2_ob  = (const float*)d_in[46];
    const float* normf_w  = (const float*)d_in[47];
    const float* head_W   = (const float*)d_in[48];
    const float* head_b   = (const float*)d_in[49];

    float* ws = (float*)d_ws;
    size_t off = 0;
    auto allocf = [&](size_t n){ float* p = ws + off; off += (n + 3) & ~(size_t)3; return p; };
    auto allocu = [&](size_t n){ return (u16*)allocf((n + 1) / 2); };

    const size_t HSZ = (size_t)NB*NT*NV*JLD;      // 1,228,800
    // fp32
    float* emb   = allocf((size_t)NB*TEMPD);
    float* memb4 = allocf((size_t)4*NB*DM);
    float* ssb8  = allocf((size_t)8*NB*2*DTR_);
    float* h     = allocf(HSZ);
    float* pre0  = allocf(HSZ);
    float* pre1  = allocf(HSZ);
    float* hm    = allocf(HSZ);
    float* qb    = allocf(HSZ);
    float* kb    = allocf(HSZ);
    float* vb    = allocf(HSZ);
    float* aty   = allocf(HSZ);
    float* fr    = allocf(HSZ);
    float* xz    = allocf((size_t)NB*NV*2*DI);
    float* xcb   = allocf((size_t)NB*NV*DI);
    float* dbc   = allocf((size_t)NB*NV*112);
    float* delta = allocf((size_t)NB*NV*DI);
    // bf16 activations
    u16* embt_bf = allocu((size_t)NB*DM);
    u16* emb1_bf = allocu((size_t)NB*TEMPD);
    u16* emb_bf  = allocu((size_t)NB*TEMPD);
    u16* semb_bf = allocu((size_t)NB*TEMPD);
    u16* hn_bf   = allocu((size_t)NB*NV*DM);
    u16* xcb_bf  = allocu((size_t)NB*NV*DI);
    u16* dbc_bf  = allocu((size_t)NB*NV*128);
    u16* y2_bf   = allocu((size_t)NB*NV*DI);
    u16* xn_bf   = allocu((size_t)NB*NT*DTR_);
    u16* sty_bf  = allocu((size_t)NB*NT*DTR_);
    u16* mid_bf  = allocu((size_t)NB*NT*DI);
    // bf16 weights (upfront, shared)
    u16* tw1   = allocu((size_t)TEMPD*DM);
    u16* tw2   = allocu((size_t)TEMPD*TEMPD);
    u16* membW = allocu((size_t)4*DM*TEMPD);
    u16* ssbW  = allocu((size_t)8*2*DTR_*TEMPD);
    // bf16 weight slabs, all 4 layers
    const size_t SLAB = (size_t)2*DI*DM + 128*DI + DI*128 + DM*DI
                      + (size_t)3*DTR_*DTR_ + 2*(size_t)DTR_*DTR_
                      + (size_t)DI*DTR_ + (size_t)DTR_*DI;
    u16* slab0 = allocu(SLAB*4);
    (void)ws_size; (void)in_sizes; (void)n_in; (void)out_size;

    // per-layer slab pointers
    u16 *s_in[4], *s_xp[4], *s_dt[4], *s_out[4], *s_qkv[4], *s_s1o[4], *s_s2o[4], *s_f1[4], *s_f2[4];
    for (int l = 0; l < 4; ++l) {
        u16* p = slab0 + SLAB*l;
        s_in[l]  = p; p += (size_t)2*DI*DM;
        s_xp[l]  = p; p += (size_t)128*DI;
        s_dt[l]  = p; p += (size_t)DI*128;
        s_out[l] = p; p += (size_t)DM*DI;
        s_qkv[l] = p; p += (size_t)3*DTR_*DTR_;
        s_s1o[l] = p; p += (size_t)DTR_*DTR_;
        s_s2o[l] = p; p += (size_t)DTR_*DTR_;
        s_f1[l]  = p; p += (size_t)DI*DTR_;
        s_f2[l]  = p;
    }

    auto tiles = [](int Kp, int Np){ return (Np/64)*(Kp/64); };

    // ---- ALL weight conversion in one launch ----
    {
        ConvTab tb; int n = 0, tot = 0;
        auto add = [&](const float* src, u16* dst, int K, int N, int Kp, int Np){
            tb.e[n] = {src, dst, K, N, Kp, Np, tot}; tot += tiles(Kp, Np); ++n;
        };
        add(time_W1, tw1, DM, TEMPD, DM, TEMPD);
        add(time_W2, tw2, TEMPD, TEMPD, TEMPD, TEMPD);
        for (int l = 0; l < 4; ++l)
            add(m_emb_W + (size_t)l*TEMPD*DM, membW + (size_t)l*DM*TEMPD, TEMPD, DM, TEMPD, DM);
        for (int l = 0; l < 4; ++l)
            add(t_s1_eW + (size_t)l*TEMPD*2*DTR_, ssbW + (size_t)l*2*DTR_*TEMPD, TEMPD, 2*DTR_, TEMPD, 2*DTR_);
        for (int l = 0; l < 4; ++l)
            add(t_s2_eW + (size_t)l*TEMPD*2*DTR_, ssbW + (size_t)(4+l)*2*DTR_*TEMPD, TEMPD, 2*DTR_, TEMPD, 2*DTR_);
        for (int l = 0; l < 4; ++l) {
            add(m_in_W   + (size_t)l*DM*2*DI,     s_in[l],  DM, 2*DI, DM, 2*DI);
            add(m_xproj_W+ (size_t)l*DI*112,      s_xp[l],  DI, 112, DI, 128);
            add(m_dt_W   + (size_t)l*DTRANK*DI,   s_dt[l],  DTRANK, DI, 128, DI);
            add(m_out_W  + (size_t)l*DI*DM,       s_out[l], DI, DM, DI, DM);
            add(t_Wq     + (size_t)l*DTR_*DTR_,   s_qkv[l],                       DTR_, DTR_, DTR_, DTR_);
            add(t_Wk     + (size_t)l*DTR_*DTR_,   s_qkv[l] + (size_t)DTR_*DTR_,   DTR_, DTR_, DTR_, DTR_);
            add(t_Wv     + (size_t)l*DTR_*DTR_,   s_qkv[l] + (size_t)2*DTR_*DTR_, DTR_, DTR_, DTR_, DTR_);
            add(t_s1_oW  + (size_t)l*DTR_*DTR_,   s_s1o[l], DTR_, DTR_, DTR_, DTR_);
            add(t_s2_oW  + (size_t)l*DTR_*DTR_,   s_s2o[l], DTR_, DTR_, DTR_, DTR_);
            add(t_fW1    + (size_t)l*DTR_*DI,     s_f1[l],  DTR_, DI, DTR_, DI);
            add(t_fW2    + (size_t)l*DI*DTR_,     s_f2[l],  DI, DTR_, DI, DTR_);
        }
        tb.n = n;
        wconv_k<<<tot, 256, 0, stream>>>(tb);
    }

    // ---- time embedding + MLP ----
    tsemb_k<<<NB, 640, 0, stream>>>(tst, embt_bf);
    G<32,ACT_SILU,4>(stream, embt_bf, DM, tw1, DM, time_b1, nullptr, 0, emb1_bf, TEMPD, NB, TEMPD, 20);
    G<32,ACT_NONE,3>(stream, emb1_bf, TEMPD, tw2, TEMPD, time_b2, emb, TEMPD, emb_bf, TEMPD, NB, TEMPD, 8);
    silu_bf_v<<<(NB*TEMPD + 255)/256, 256, 0, stream>>>(emb, semb_bf, NB*TEMPD);

    // ---- hoisted per-layer emb projections ----
    {
        dim3 g1(DM/128, 1, 4), b(256);
        gemm_memb_bk<<<g1, b, 0, stream>>>(emb_bf, membW, m_emb_b, memb4);
        dim3 g2((2*DTR_)/128, 1, 8);
        gemm_ssb_bk<<<g2, b, 0, stream>>>(semb_bf, ssbW, t_s1_eb, t_s2_eb, ssb8);
    }

    // ---- vertex embedding + VORDER gather (writes h and pre0) ----
    embed_k<<<NB*NT*NV, 64, 0, stream>>>(x, seq_emb, emb_W, emb_b, h, pre0);

    for (int i = 0; i < 4; ++i) {
        // ---- mamba half ----
        rms_t_k<<<NB*NV, 256, 0, stream>>>(h, m_norm_w + (size_t)i*DM,
                                           memb4 + (size_t)i*NB*DM, hm, hn_bf);
        G<64,ACT_NONE,0>(stream, hn_bf, DM, s_in[i], DM, nullptr, xz, 2*DI, nullptr, 0, NB*NV, 2*DI, 20);
        convsilu_k<<<(NB*NV*DI + 255)/256, 256, 0, stream>>>(
            xz, m_conv_w + (size_t)i*DI*4, m_conv_b + (size_t)i*DI, xcb, xcb_bf);
        zero_k<<<(NB*NV*112 + 255)/256, 256, 0, stream>>>(dbc, NB*NV*112);
        G<32,ACT_NONE,2>(stream, xcb_bf, DI, s_xp[i], DI, nullptr, dbc, 112, nullptr, 0, NB*NV, 112, 5, 8);
        dbcconv_k<<<(NB*NV*128 + 255)/256, 256, 0, stream>>>(dbc, dbc_bf);
        G<64,ACT_SOFTPLUS,0>(stream, dbc_bf, 128, s_dt[i], 128, m_dt_b + (size_t)i*DI,
                             delta, DI, nullptr, 0, NB*NV, DI, 2);
        scan_k<<<NB*10, 256, 0, stream>>>(delta, dbc, xcb, xz,
             m_A_log + (size_t)i*DI*DSTATE, m_D + (size_t)i*DI, y2_bf);
        G<32,ACT_NONE,1>(stream, y2_bf, DI, s_out[i], DI, nullptr, hm, DM, nullptr, 0, NB*NV, DM, 40);
        hm2ht_ln_k<<<NB*NT, 256, 0, stream>>>(hm, t_ln1_w + (size_t)i*DTR_, t_ln1_b + (size_t)i*DTR_,
                                              h, xn_bf);

        // ---- transformer half ----
        {
            dim3 g(DTR_/128, (NB*NT)/32, 3), b(256);
            gemm_qkv_bk<<<g, b, 0, stream>>>(xn_bf, s_qkv[i],
                t_bq + (size_t)i*DTR_, t_bk + (size_t)i*DTR_, t_bv + (size_t)i*DTR_,
                qb, kb, vb);
        }
        attn_k<<<NB*NT*NHEAD_, 64, 0, stream>>>(qb, kb, vb, aty);

        sty_ln_k<<<NB*NT, 256, 0, stream>>>(aty, t_s1_lw + (size_t)i*DTR_, t_s1_lb + (size_t)i*DTR_,
                                            ssb8 + (size_t)i*NB*2*DTR_, sty_bf);
        G<32,ACT_NONE,1>(stream, sty_bf, DTR_, s_s1o[i], DTR_, t_s1_ob + (size_t)i*DTR_,
                         h, DTR_, nullptr, 0, NB*NT, DTR_, 30);

        ln_bf_k<<<NB*NT, 256, 0, stream>>>(h, t_ln2_w + (size_t)i*DTR_, t_ln2_b + (size_t)i*DTR_, xn_bf, DTR_);
        G<32,ACT_GELU,4>(stream, xn_bf, DTR_, s_f1[i], DTR_, t_fb1 + (size_t)i*DI,
                         nullptr, 0, mid_bf, DI, NB*NT, DI, 30);
        G<32,ACT_NONE,0>(stream, mid_bf, DI, s_f2[i], DI, t_fb2 + (size_t)i*DTR_,
                         aty, DTR_, nullptr, 0, NB*NT, DTR_, 40);

        sty_ln_k<<<NB*NT, 256, 0, stream>>>(aty, t_s2_lw + (size_t)i*DTR_, t_s2_lb + (size_t)i*DTR_,
                                            ssb8 + (size_t)(4 + i)*NB*2*DTR_, sty_bf);
        // final h-update of the layer, with fused skip logic
        if (i == 0)
            G<32,ACT_NONE,6>(stream, sty_bf, DTR_, s_s2o[i], DTR_, t_s2_ob + (size_t)i*DTR_,
                             h, DTR_, nullptr, 0, NB*NT, DTR_, 30, 1, pre1);
        else if (i == 2)
            G<32,ACT_NONE,5>(stream, sty_bf, DTR_, s_s2o[i], DTR_, t_s2_ob + (size_t)i*DTR_,
                             h, DTR_, nullptr, 0, NB*NT, DTR_, 30, 1, pre1);
        else if (i == 3)
            G<32,ACT_NONE,5>(stream, sty_bf, DTR_, s_s2o[i], DTR_, t_s2_ob + (size_t)i*DTR_,
                             h, DTR_, nullptr, 0, NB*NT, DTR_, 30, 1, pre0);
        else
            G<32,ACT_NONE,1>(stream, sty_bf, DTR_, s_s2o[i], DTR_, t_s2_ob + (size_t)i*DTR_,
                             h, DTR_, nullptr, 0, NB*NT, DTR_, 30);
    }

    // final rmsnorm + REV gather + head
    rms_f_k<<<NB*NT, 256, 0, stream>>>(h, normf_w, fr, DTR_);
    head_k<<<NB*NT, 48, 0, stream>>>(fr, head_W, head_b, (float*)d_out);
}